// Round 2
// baseline (456.007 us; speedup 1.0000x reference)
//
#include <hip/hip_runtime.h>
#include <hip/hip_bf16.h>
#include <math.h>

// Problem constants
#define NTOK   8192      // B*S
#define HID    2048
#define DWN    512
#define NEXP   16
#define PADSLOT 18432    // 144*128 >= 16384 + 16*127 (segments 128-aligned)
#define NSLOTBLK 144     // PADSLOT/128
#define DGRID_HALF (NSLOTBLK * 4)   // 576 blocks per K-half (slot-blocks x out-blocks)

// ws layout (bytes). H overlays DWB (dwb dead after down_mfma; combine writes h after).
#define OFF_XB       0                       // bf16[NTOK*HID]       = 33554432
#define OFF_DWB      33554432                // bf16[NEXP*DWN*HID]   = 33554432
#define OFF_H        33554432                // bf16[NTOK*DWN]       = 8388608 (overlay on DWB)
#define OFF_UWB      67108864                // bf16[HID*DWN]        = 2097152
#define OFF_TOK      69206016                // int[PADSLOT]         = 73728
#define OFF_SPOS     69279744                // int2[NTOK]           = 65536
#define OFF_EIDX     69345280                // int2[NTOK]           = 65536
#define OFF_PVAL     69410816                // float2[NTOK]         = 65536
#define OFF_COUNTS   69476352                // int[16]
#define OFF_BASE     69476416                // int[17] (padded to 128)
#define OFF_CURSOR   69476544                // int[16]
#define OFF_COLSUM   69476608                // float[16]
#define OFF_SEG      69476672                // bf16[ksplit][PADSLOT*512]
#define SEGHALF_SHORTS 9437184               // PADSLOT*512
#define SEGHALF_BYTES  18874368
#define WS_NEED1     (OFF_SEG + 1 * SEGHALF_BYTES)   //  88.4 MB
#define WS_NEED2     (OFF_SEG + 2 * SEGHALF_BYTES)   // 107.2 MB

typedef __attribute__((ext_vector_type(8))) __bf16 bf16x8;
typedef __attribute__((ext_vector_type(4))) float f32x4;

// async 16B/lane global->LDS copy (LDS dest is wave-uniform base; HW adds lane*16)
#define ASYNC16(gsrc, ldst) \
  __builtin_amdgcn_global_load_lds((const __attribute__((address_space(1))) unsigned int*)(gsrc), \
                                   (__attribute__((address_space(3))) unsigned int*)(ldst), 16, 0, 0)

__device__ inline unsigned short f2bf(float f) {
  unsigned int u = __float_as_uint(f);
  unsigned int r = (u + 0x7FFFu + ((u >> 16) & 1u)) >> 16;
  return (unsigned short)r;
}
__device__ inline float bf2f(unsigned short s) {
  return __uint_as_float((unsigned int)s << 16);
}

// ---------------- fp32 -> bf16 cast, 8 elems/thread ----------------
__global__ __launch_bounds__(256) void cast8_kernel(const float* __restrict__ src,
                                                    unsigned short* __restrict__ dst)
{
  size_t i = ((size_t)blockIdx.x * 256 + threadIdx.x) * 8;
  float4 a = *(const float4*)(src + i);
  float4 b = *(const float4*)(src + i + 4);
  unsigned short o[8];
  o[0]=f2bf(a.x); o[1]=f2bf(a.y); o[2]=f2bf(a.z); o[3]=f2bf(a.w);
  o[4]=f2bf(b.x); o[5]=f2bf(b.y); o[6]=f2bf(b.z); o[7]=f2bf(b.w);
  *(uint4*)(dst + i) = *(const uint4*)o;
}

// ---------------- gating: FROZEN selection math from R3 (bit-identical, passed repeatedly) ----
// Now ALSO writes the bf16 cast of x (xbw) -- saves a separate 100MB-traffic cast launch.
// Cast uses the same f2bf rounding as cast8_kernel -> bit-identical xb.
__global__ __launch_bounds__(256) void gate_kernel(
    const float* __restrict__ x, const float* __restrict__ gw,
    int2* __restrict__ eidx, float2* __restrict__ pvals,
    unsigned short* __restrict__ xbw)
{
  int lane = threadIdx.x & 63;
  int wave = threadIdx.x >> 6;
  int n = blockIdx.x * 4 + wave;
  const float* xr  = x + (size_t)n * HID;
  unsigned short* xw = xbw + (size_t)n * HID;
  const float* gwp = gw + lane;

  double a0=0,a1=0,a2=0,a3=0,a4=0,a5=0,a6=0,a7=0;
  double a8=0,a9=0,a10=0,a11=0,a12=0,a13=0,a14=0,a15=0;

  for (int d0 = 0; d0 < HID; d0 += 64) {
    float xv = xr[d0 + lane];
    xw[d0 + lane] = f2bf(xv);
    double xd = (double)xv;
    const float* g = gwp + d0;
    a0  = fma(xd, (double)g[ 0*HID], a0);
    a1  = fma(xd, (double)g[ 1*HID], a1);
    a2  = fma(xd, (double)g[ 2*HID], a2);
    a3  = fma(xd, (double)g[ 3*HID], a3);
    a4  = fma(xd, (double)g[ 4*HID], a4);
    a5  = fma(xd, (double)g[ 5*HID], a5);
    a6  = fma(xd, (double)g[ 6*HID], a6);
    a7  = fma(xd, (double)g[ 7*HID], a7);
    a8  = fma(xd, (double)g[ 8*HID], a8);
    a9  = fma(xd, (double)g[ 9*HID], a9);
    a10 = fma(xd, (double)g[10*HID], a10);
    a11 = fma(xd, (double)g[11*HID], a11);
    a12 = fma(xd, (double)g[12*HID], a12);
    a13 = fma(xd, (double)g[13*HID], a13);
    a14 = fma(xd, (double)g[14*HID], a14);
    a15 = fma(xd, (double)g[15*HID], a15);
  }

#define RED(v) { v += __shfl_xor(v,32,64); v += __shfl_xor(v,16,64); v += __shfl_xor(v,8,64); \
                 v += __shfl_xor(v,4,64);  v += __shfl_xor(v,2,64);  v += __shfl_xor(v,1,64); }
  RED(a0) RED(a1) RED(a2) RED(a3) RED(a4) RED(a5) RED(a6) RED(a7)
  RED(a8) RED(a9) RED(a10) RED(a11) RED(a12) RED(a13) RED(a14) RED(a15)
#undef RED

  if (lane == 0) {
    double v0 = -1e300, v1 = -1e300;
    int i0 = 0, i1 = 0;
#define TOP(v,E) { if ((v) > v0) { v1 = v0; i1 = i0; v0 = (v); i0 = (E); } \
                   else if ((v) > v1) { v1 = (v); i1 = (E); } }
    TOP(a0,0) TOP(a1,1) TOP(a2,2) TOP(a3,3) TOP(a4,4) TOP(a5,5) TOP(a6,6) TOP(a7,7)
    TOP(a8,8) TOP(a9,9) TOP(a10,10) TOP(a11,11) TOP(a12,12) TOP(a13,13) TOP(a14,14) TOP(a15,15)
#undef TOP
    double ex = exp(v1 - v0);
    double denom = 1.0 + ex;
    eidx[n]  = make_int2(i0, i1);
    pvals[n] = make_float2((float)(1.0 / denom), (float)(ex / denom));
  }
}

// ---------------- histogram: counts + colsum via LDS bins ----------------
__global__ __launch_bounds__(256) void hist_kernel(
    const int2* __restrict__ eidx, const float2* __restrict__ pvals,
    int* __restrict__ counts, float* __restrict__ colsum)
{
  __shared__ int   cbin[NEXP];
  __shared__ float lbin[NEXP];
  if (threadIdx.x < NEXP) { cbin[threadIdx.x] = 0; lbin[threadIdx.x] = 0.f; }
  __syncthreads();
  int n = blockIdx.x * 256 + threadIdx.x;
  int2 e = eidx[n];
  float2 p = pvals[n];
  atomicAdd(&cbin[e.x], 1);  atomicAdd(&lbin[e.x], p.x);
  atomicAdd(&cbin[e.y], 1);  atomicAdd(&lbin[e.y], p.y);
  __syncthreads();
  if (threadIdx.x < NEXP) {
    atomicAdd(&counts[threadIdx.x], cbin[threadIdx.x]);
    atomicAdd(&colsum[threadIdx.x], lbin[threadIdx.x]);
  }
}

// ---------------- scan bases (128-aligned segments) + loss ----------------
__global__ void scan_loss_kernel(const int* __restrict__ counts, int* __restrict__ base,
                                 const float* __restrict__ colsum, float* __restrict__ loss_out)
{
  if (threadIdx.x == 0 && blockIdx.x == 0) {
    int acc = 0;
    for (int e = 0; e < NEXP; e++) { base[e] = acc; acc += (counts[e] + 127) & ~127; }
    base[NEXP] = acc;
    double s = 0.0;
    for (int e = 0; e < NEXP; e++) { double c = (double)colsum[e]; s += c * c; }
    loss_out[0] = (float)(1.6 * s / ((double)NTOK * (double)NTOK));
  }
}

// ---------------- scatter: wave-aggregated cursor atomics; records slot positions ----------------
__global__ __launch_bounds__(256) void scatter_kernel(
    const int2* __restrict__ eidx, const int* __restrict__ base, int* __restrict__ cursor,
    int* __restrict__ tok, int2* __restrict__ spos)
{
  int n = blockIdx.x * 256 + threadIdx.x;
  int lane = threadIdx.x & 63;
  int2 e = eidx[n];
  int myE[2] = {e.x, e.y};
  int myPos[2];
#pragma unroll
  for (int s = 0; s < 2; s++) {
    int eq = myE[s];
#pragma unroll
    for (int q = 0; q < NEXP; q++) {
      unsigned long long m = __ballot(eq == q);
      if (eq == q) {
        int cnt = __popcll(m);
        int pre = __popcll(m & ((1ull << lane) - 1ull));
        int b = 0;
        if (pre == 0) b = atomicAdd(&cursor[q], cnt);
        int leader = __ffsll((long long)m) - 1;
        b = __shfl(b, leader, 64);
        int pos = base[q] + b + pre;
        tok[pos] = n;
        myPos[s] = pos;
      }
    }
  }
  spos[n] = make_int2(myPos[0], myPos[1]);
}

// ---------------- grouped expert down-proj: bf16 MFMA, 128x128 tile, BK=64, split-K ----------------
// XCD-chunked bijective swizzle (nwg = 8 * cpx exactly): each XCD gets a contiguous run of
// logical block ids. Within a run, out-block varies FASTEST -> the 4 blocks sharing one
// gathered A slot-tile are temporally + XCD adjacent (A hits L2 instead of 4x HBM re-fetch),
// and an expert's B panel stays L2-resident across consecutive slot-groups.
// T3 minimum-2-phase dbuf staging retained from R1.
__global__ __launch_bounds__(256) void down_mfma_kernel(
    const unsigned short* __restrict__ xb, const unsigned short* __restrict__ dwb,
    const int* __restrict__ base, const int* __restrict__ tok,
    unsigned short* __restrict__ seg, int kcount)
{
  __shared__ unsigned short smem[32768];   // 2 x (A[8192] + B[8192]); epilogue overlays 128x136=17408

  // grid is 1-D: DGRID_HALF * ksplit blocks (1152 or 576; both divisible by 8)
  int wg  = blockIdx.x;
  int cpx = gridDim.x >> 3;                 // blocks per XCD chunk
  int logical = (wg & 7) * cpx + (wg >> 3); // bijective XCD chunking
  int kh      = logical / DGRID_HALF;
  int r       = logical % DGRID_HALF;
  int slot0   = (r >> 2) * 128;             // slot-group
  int out0    = (r & 3) * 128;              // out-block fastest (A-tile reuse)

  if (slot0 >= base[NEXP]) return;          // uniform per block
  int e = 0;
#pragma unroll
  for (int q = 1; q < NEXP; q++) if (base[q] <= slot0) e = q;
  int kbase = kh * kcount * 64;

  int tid = threadIdx.x;
  const int l = tid & 63, w = tid >> 6;
  const int wm = w & 1, wn = w >> 1;
  const int lm = l & 15, quad = l >> 4;

  const unsigned short* agp[4];
  const unsigned short* bgp[4];
#pragma unroll
  for (int i = 0; i < 4; i++) {
    int g = w * 4 + i;
    int rr = g * 8 + (l & 7);
    int kc = l >> 3;
    int t = tok[slot0 + rr];
    agp[i] = xb + (size_t)(t < 0 ? 0 : t) * HID + kbase + kc * 8;
    bgp[i] = dwb + ((size_t)e * DWN + out0 + rr) * HID + kbase + kc * 8;
  }

  int am_off[4], bn_off[4];
#pragma unroll
  for (int mi = 0; mi < 4; mi++) {
    int m = wm * 64 + mi * 16 + lm;
    am_off[mi] = (m >> 3) * 512 + (m & 7) * 8 + quad * 64;
    int nn = wn * 64 + mi * 16 + lm;
    bn_off[mi] = (nn >> 3) * 512 + (nn & 7) * 8 + quad * 64;
  }

  f32x4 acc[4][4] = {};

  // prologue: stage K-tile 0 into buffer 0
#pragma unroll
  for (int i = 0; i < 4; i++) {
    int g = w * 4 + i;
    ASYNC16(agp[i], &smem[g * 512]);
    ASYNC16(bgp[i], &smem[8192 + g * 512]);
  }
  __syncthreads();                       // vmcnt(0): buf0 ready

  int cur = 0;
  for (int it = 0; it < kcount; it++) {
    unsigned short* As = smem + cur * 16384;
    unsigned short* Bs = As + 8192;
    // prefetch next K-tile into the other buffer (overlaps with compute below)
    if (it + 1 < kcount) {
      int k0 = (it + 1) * 64;
      unsigned short* Ap = smem + (cur ^ 1) * 16384;
#pragma unroll
      for (int i = 0; i < 4; i++) {
        int g = w * 4 + i;
        ASYNC16(agp[i] + k0, &Ap[g * 512]);
        ASYNC16(bgp[i] + k0, &Ap[8192 + g * 512]);
      }
    }
#pragma unroll
    for (int kk = 0; kk < 2; kk++) {
      bf16x8 af[4], bfr[4];
#pragma unroll
      for (int mi = 0; mi < 4; mi++) af[mi]  = *(const bf16x8*)&As[am_off[mi] + kk * 256];
#pragma unroll
      for (int ni = 0; ni < 4; ni++) bfr[ni] = *(const bf16x8*)&Bs[bn_off[ni] + kk * 256];
#pragma unroll
      for (int mi = 0; mi < 4; mi++)
#pragma unroll
        for (int ni = 0; ni < 4; ni++)
          acc[mi][ni] = __builtin_amdgcn_mfma_f32_16x16x32_bf16(af[mi], bfr[ni], acc[mi][ni], 0, 0, 0);
    }
    __syncthreads();                    // all reads of buf[cur] done; buf[cur^1] loads drained
    cur ^= 1;
  }

  // epilogue: stage bf16 tile in LDS (stride 136 shorts = 272B, 16B-aligned, bank-spread),
  // then fully-coalesced 16B global stores. No atomics. (loop-end barrier already synced)
#pragma unroll
  for (int mi = 0; mi < 4; mi++)
#pragma unroll
    for (int reg = 0; reg < 4; reg++) {
      int m = wm * 64 + mi * 16 + quad * 4 + reg;
#pragma unroll
      for (int ni = 0; ni < 4; ni++) {
        int c = wn * 64 + ni * 16 + lm;
        smem[m * 136 + c] = f2bf(acc[mi][ni][reg]);
      }
    }
  __syncthreads();
#pragma unroll
  for (int it2 = 0; it2 < 8; it2++) {
    int chunk = it2 * 256 + tid;
    int row = chunk >> 4, off = (chunk & 15) * 8;
    uint4 v = *(const uint4*)&smem[row * 136 + off];
    *(uint4*)&seg[(size_t)kh * SEGHALF_SHORTS + (size_t)(slot0 + row) * 512 + out0 + off] = v;
  }
}

// ---------------- combine (gather 2 slots x ksplit halves) + bias + gelu_new -> h bf16 ----------------
__global__ __launch_bounds__(256) void combine_gelu_kernel(
    const unsigned short* __restrict__ seg, const int2* __restrict__ spos,
    const float2* __restrict__ pv, const int2* __restrict__ eix,
    const float* __restrict__ db, unsigned short* __restrict__ h, int ksplit)
{
  int n = blockIdx.x * 4 + (threadIdx.x >> 6);
  int lane = threadIdx.x & 63;
  int c0 = lane * 8;
  int2 sp = spos[n];
  float2 p = pv[n];
  int2 e = eix[n];

  float d0[8] = {0,0,0,0,0,0,0,0}, d1[8] = {0,0,0,0,0,0,0,0};
  for (int hh = 0; hh < ksplit; hh++) {
    uint4 u0 = *(const uint4*)(seg + (size_t)hh * SEGHALF_SHORTS + (size_t)sp.x * 512 + c0);
    uint4 u1 = *(const uint4*)(seg + (size_t)hh * SEGHALF_SHORTS + (size_t)sp.y * 512 + c0);
    const unsigned short* s0 = (const unsigned short*)&u0;
    const unsigned short* s1 = (const unsigned short*)&u1;
#pragma unroll
    for (int j = 0; j < 8; j++) { d0[j] += bf2f(s0[j]); d1[j] += bf2f(s1[j]); }
  }
  float b0[8], b1[8];
  *(float4*)&b0[0] = *(const float4*)(db + e.x * DWN + c0);
  *(float4*)&b0[4] = *(const float4*)(db + e.x * DWN + c0 + 4);
  *(float4*)&b1[0] = *(const float4*)(db + e.y * DWN + c0);
  *(float4*)&b1[4] = *(const float4*)(db + e.y * DWN + c0 + 4);

  unsigned short o[8];
#pragma unroll
  for (int j = 0; j < 8; j++) {
    float xx = p.x * (d0[j] + b0[j]) + p.y * (d1[j] + b1[j]);
    float inner = 0.7978845608028654f * (xx + 0.044715f * xx * xx * xx);
    o[j] = f2bf(0.5f * xx * (1.0f + tanhf(inner)));
  }
  *(uint4*)(h + (size_t)n * DWN + c0) = *(const uint4*)o;
}

// ---------------- up-proj: bf16 MFMA, 128x128 tile, BK=64, K=512, dbuf-prefetch ----------------
// XCD-chunked swizzle (1024 = 8*128): col-block fastest within a chunk -> the 16 blocks
// sharing one h A-tile are XCD+temporally adjacent; uwb (2MB) becomes L2-resident per XCD.
__global__ __launch_bounds__(256) void up_mfma_kernel(
    const unsigned short* __restrict__ h, const unsigned short* __restrict__ uwb,
    const float* __restrict__ ub, float* __restrict__ out)
{
  __shared__ unsigned short smem[32768];   // 2 x (A[8192] + B[8192])

  int wg  = blockIdx.x;                    // grid = 1024
  int cpx = gridDim.x >> 3;                // 128
  int logical = (wg & 7) * cpx + (wg >> 3);
  int row0 = (logical >> 4) * 128;
  int col0 = (logical & 15) * 128;

  int tid = threadIdx.x;
  const int l = tid & 63, w = tid >> 6;
  const int wm = w & 1, wn = w >> 1;
  const int lm = l & 15, quad = l >> 4;

  const unsigned short* agp[4];
  const unsigned short* bgp[4];
#pragma unroll
  for (int i = 0; i < 4; i++) {
    int g = w * 4 + i;
    int rr = g * 8 + (l & 7);
    int kc = l >> 3;
    agp[i] = h   + (size_t)(row0 + rr) * DWN + kc * 8;
    bgp[i] = uwb + (size_t)(col0 + rr) * DWN + kc * 8;
  }

  int am_off[4], bn_off[4];
#pragma unroll
  for (int mi = 0; mi < 4; mi++) {
    int m = wm * 64 + mi * 16 + lm;
    am_off[mi] = (m >> 3) * 512 + (m & 7) * 8 + quad * 64;
    int nn = wn * 64 + mi * 16 + lm;
    bn_off[mi] = (nn >> 3) * 512 + (nn & 7) * 8 + quad * 64;
  }

  f32x4 acc[4][4] = {};

  // prologue: stage K-tile 0 into buffer 0
#pragma unroll
  for (int i = 0; i < 4; i++) {
    int g = w * 4 + i;
    ASYNC16(agp[i], &smem[g * 512]);
    ASYNC16(bgp[i], &smem[8192 + g * 512]);
  }
  __syncthreads();

  int cur = 0;
  for (int k0 = 0; k0 < DWN; k0 += 64) {
    unsigned short* As = smem + cur * 16384;
    unsigned short* Bs = As + 8192;
    if (k0 + 64 < DWN) {
      unsigned short* Ap = smem + (cur ^ 1) * 16384;
#pragma unroll
      for (int i = 0; i < 4; i++) {
        int g = w * 4 + i;
        ASYNC16(agp[i] + k0 + 64, &Ap[g * 512]);
        ASYNC16(bgp[i] + k0 + 64, &Ap[8192 + g * 512]);
      }
    }
#pragma unroll
    for (int kk = 0; kk < 2; kk++) {
      bf16x8 af[4], bfr[4];
#pragma unroll
      for (int mi = 0; mi < 4; mi++) af[mi]  = *(const bf16x8*)&As[am_off[mi] + kk * 256];
#pragma unroll
      for (int ni = 0; ni < 4; ni++) bfr[ni] = *(const bf16x8*)&Bs[bn_off[ni] + kk * 256];
#pragma unroll
      for (int mi = 0; mi < 4; mi++)
#pragma unroll
        for (int ni = 0; ni < 4; ni++)
          acc[mi][ni] = __builtin_amdgcn_mfma_f32_16x16x32_bf16(af[mi], bfr[ni], acc[mi][ni], 0, 0, 0);
    }
    __syncthreads();
    cur ^= 1;
  }

  float ubv[4];
#pragma unroll
  for (int ni = 0; ni < 4; ni++)
    ubv[ni] = ub[col0 + wn * 64 + ni * 16 + lm];
#pragma unroll
  for (int mi = 0; mi < 4; mi++) {
#pragma unroll
    for (int reg = 0; reg < 4; reg++) {
      int m = row0 + wm * 64 + mi * 16 + quad * 4 + reg;
      float* orow = out + (size_t)m * HID;
#pragma unroll
      for (int ni = 0; ni < 4; ni++) {
        int gc = col0 + wn * 64 + ni * 16 + lm;
        orow[gc] = acc[mi][ni][reg] + ubv[ni];
      }
    }
  }
}

extern "C" void kernel_launch(void* const* d_in, const int* in_sizes, int n_in,
                              void* d_out, int out_size, void* d_ws, size_t ws_size,
                              hipStream_t stream)
{
  const float* x  = (const float*)d_in[0];
  const float* gw = (const float*)d_in[1];
  const float* dw = (const float*)d_in[2];
  const float* db = (const float*)d_in[3];
  const float* uw = (const float*)d_in[4];
  const float* ub = (const float*)d_in[5];
  float* out = (float*)d_out;

  char* ws = (char*)d_ws;
  unsigned short* xb   = (unsigned short*)(ws + OFF_XB);
  unsigned short* dwb  = (unsigned short*)(ws + OFF_DWB);
  unsigned short* uwb  = (unsigned short*)(ws + OFF_UWB);
  unsigned short* h    = (unsigned short*)(ws + OFF_H);
  unsigned short* seg  = (unsigned short*)(ws + OFF_SEG);
  int*    tok    = (int*)(ws + OFF_TOK);
  int2*   spos   = (int2*)(ws + OFF_SPOS);
  int2*   eidx   = (int2*)(ws + OFF_EIDX);
  float2* pvals  = (float2*)(ws + OFF_PVAL);
  int*    counts = (int*)(ws + OFF_COUNTS);
  int*    base   = (int*)(ws + OFF_BASE);
  int*    cursor = (int*)(ws + OFF_CURSOR);
  float*  colsum = (float*)(ws + OFF_COLSUM);

  // split-K only if the workspace is big enough (ws_size constant per session -> same work each call)
  const int ksplit = (ws_size >= (size_t)WS_NEED2) ? 2 : 1;
  const int kcount = (HID / 64) / ksplit;

  hipMemsetAsync(tok, 0xFF, PADSLOT * sizeof(int), stream);     // token = -1 padding
  hipMemsetAsync(counts, 0, 320, stream);                        // counts/base/cursor/colsum

  // x cast is fused into gate_kernel (reads x once, writes xb)
  cast8_kernel<<<(NEXP * DWN * HID) / 8 / 256, 256, 0, stream>>>(dw, dwb);
  cast8_kernel<<<(HID * DWN) / 8 / 256, 256, 0, stream>>>(uw, uwb);

  gate_kernel<<<NTOK / 4, 256, 0, stream>>>(x, gw, eidx, pvals, xb);
  hist_kernel<<<NTOK / 256, 256, 0, stream>>>(eidx, pvals, counts, colsum);
  scan_loss_kernel<<<1, 64, 0, stream>>>(counts, base, colsum, out + (size_t)NTOK * HID);
  scatter_kernel<<<NTOK / 256, 256, 0, stream>>>(eidx, base, cursor, tok, spos);

  down_mfma_kernel<<<DGRID_HALF * ksplit, 256, 0, stream>>>(xb, dwb, base, tok, seg, kcount);

  combine_gelu_kernel<<<NTOK / 4, 256, 0, stream>>>(seg, spos, pvals, eidx, db, h, ksplit);

  up_mfma_kernel<<<NTOK / 128 * (HID / 128), 256, 0, stream>>>(h, uwb, ub, out);
}

// Round 3
// 453.150 us; speedup vs baseline: 1.0063x; 1.0063x over previous
//
#include <hip/hip_runtime.h>
#include <hip/hip_bf16.h>
#include <math.h>

// Problem constants
#define NTOK   8192      // B*S
#define HID    2048
#define DWN    512
#define NEXP   16
#define PADSLOT 18432    // 144*128 >= 16384 + 16*127 (segments 128-aligned)
#define NSLOTBLK 144     // PADSLOT/128
#define DGRID_HALF (NSLOTBLK * 4)   // 576 blocks per K-half (slot-blocks x out-blocks)

// ws layout (bytes). H overlays DWB (dwb dead after down_mfma; combine writes h after).
#define OFF_XB       0                       // bf16[NTOK*HID]       = 33554432
#define OFF_DWB      33554432                // bf16[NEXP*DWN*HID]   = 33554432
#define OFF_H        33554432                // bf16[NTOK*DWN]       = 8388608 (overlay on DWB)
#define OFF_UWB      67108864                // bf16[HID*DWN]        = 2097152
#define OFF_TOK      69206016                // int[PADSLOT]         = 73728
#define OFF_SPOS     69279744                // int2[NTOK]           = 65536
#define OFF_EIDX     69345280                // int2[NTOK]           = 65536
#define OFF_PVAL     69410816                // float2[NTOK]         = 65536
#define OFF_COUNTS   69476352                // int[16]
#define OFF_BASE     69476416                // int[17] (padded to 128)
#define OFF_CURSOR   69476544                // int[16]
#define OFF_COLSUM   69476608                // float[16]
#define OFF_SEG      69476672                // bf16[ksplit][PADSLOT*512]
#define SEGHALF_SHORTS 9437184               // PADSLOT*512
#define SEGHALF_BYTES  18874368
#define WS_NEED1     (OFF_SEG + 1 * SEGHALF_BYTES)   //  88.4 MB
#define WS_NEED2     (OFF_SEG + 2 * SEGHALF_BYTES)   // 107.2 MB

typedef __attribute__((ext_vector_type(8))) __bf16 bf16x8;
typedef __attribute__((ext_vector_type(4))) float f32x4;

// async 16B/lane global->LDS copy (LDS dest is wave-uniform base; HW adds lane*16)
#define ASYNC16(gsrc, ldst) \
  __builtin_amdgcn_global_load_lds((const __attribute__((address_space(1))) unsigned int*)(gsrc), \
                                   (__attribute__((address_space(3))) unsigned int*)(ldst), 16, 0, 0)

__device__ inline unsigned short f2bf(float f) {
  unsigned int u = __float_as_uint(f);
  unsigned int r = (u + 0x7FFFu + ((u >> 16) & 1u)) >> 16;
  return (unsigned short)r;
}
__device__ inline float bf2f(unsigned short s) {
  return __uint_as_float((unsigned int)s << 16);
}

// ---------------- fp32 -> bf16 cast, 8 elems/thread ----------------
__global__ __launch_bounds__(256) void cast8_kernel(const float* __restrict__ src,
                                                    unsigned short* __restrict__ dst)
{
  size_t i = ((size_t)blockIdx.x * 256 + threadIdx.x) * 8;
  float4 a = *(const float4*)(src + i);
  float4 b = *(const float4*)(src + i + 4);
  unsigned short o[8];
  o[0]=f2bf(a.x); o[1]=f2bf(a.y); o[2]=f2bf(a.z); o[3]=f2bf(a.w);
  o[4]=f2bf(b.x); o[5]=f2bf(b.y); o[6]=f2bf(b.z); o[7]=f2bf(b.w);
  *(uint4*)(dst + i) = *(const uint4*)o;
}

// ---------------- gating: 2 tokens/wave, float4 loads, f64 accumulation ----------------
// R2 restructure: g float4 is loaded+converted ONCE and FMA'd into both tokens' accs ->
// halves the per-wave 128KB gate-weight L2 re-read (1.07GB -> 512MB) and cuts load-instr
// count 4x. f64 accumulation retained: summation-order change perturbs logits ~1e-15 rel,
// far below top-2 selection separation. Fused bf16 x-cast uses identical f2bf -> xb bit-same.
__global__ __launch_bounds__(256, 4) void gate_kernel(
    const float* __restrict__ x, const float* __restrict__ gw,
    int2* __restrict__ eidx, float2* __restrict__ pvals,
    unsigned short* __restrict__ xbw)
{
  int lane = threadIdx.x & 63;
  int wave = threadIdx.x >> 6;
  int n0 = (blockIdx.x * 4 + wave) * 2;          // 2 tokens per wave
  const float* xr0 = x + (size_t)n0 * HID;
  const float* xr1 = xr0 + HID;
  unsigned short* xw0 = xbw + (size_t)n0 * HID;
  unsigned short* xw1 = xw0 + HID;

  double acc0[NEXP], acc1[NEXP];
#pragma unroll
  for (int e = 0; e < NEXP; e++) { acc0[e] = 0.0; acc1[e] = 0.0; }

  for (int d0 = 0; d0 < HID; d0 += 256) {
    int d = d0 + lane * 4;
    float4 xv0 = *(const float4*)(xr0 + d);
    float4 xv1 = *(const float4*)(xr1 + d);
    unsigned short o0[4] = {f2bf(xv0.x), f2bf(xv0.y), f2bf(xv0.z), f2bf(xv0.w)};
    unsigned short o1[4] = {f2bf(xv1.x), f2bf(xv1.y), f2bf(xv1.z), f2bf(xv1.w)};
    *(uint2*)(xw0 + d) = *(const uint2*)o0;
    *(uint2*)(xw1 + d) = *(const uint2*)o1;
    double x00 = (double)xv0.x, x01 = (double)xv0.y, x02 = (double)xv0.z, x03 = (double)xv0.w;
    double x10 = (double)xv1.x, x11 = (double)xv1.y, x12 = (double)xv1.z, x13 = (double)xv1.w;
#pragma unroll
    for (int e = 0; e < NEXP; e++) {
      float4 g = *(const float4*)(gw + (size_t)e * HID + d);
      double g0 = (double)g.x, g1 = (double)g.y, g2 = (double)g.z, g3 = (double)g.w;
      double s0 = acc0[e], s1 = acc1[e];
      s0 = fma(x00, g0, s0); s0 = fma(x01, g1, s0);
      s0 = fma(x02, g2, s0); s0 = fma(x03, g3, s0);
      s1 = fma(x10, g0, s1); s1 = fma(x11, g1, s1);
      s1 = fma(x12, g2, s1); s1 = fma(x13, g3, s1);
      acc0[e] = s0; acc1[e] = s1;
    }
  }

  // butterfly reduce across 64 lanes (all lanes end with the totals)
#define RED(v) { v += __shfl_xor(v,32,64); v += __shfl_xor(v,16,64); v += __shfl_xor(v,8,64); \
                 v += __shfl_xor(v,4,64);  v += __shfl_xor(v,2,64);  v += __shfl_xor(v,1,64); }
#pragma unroll
  for (int e = 0; e < NEXP; e++) { RED(acc0[e]) RED(acc1[e]) }
#undef RED

#define TOPSEL(ACC, N) { \
    double v0 = -1e300, v1 = -1e300; int i0 = 0, i1 = 0; \
    _Pragma("unroll") \
    for (int e = 0; e < NEXP; e++) { \
      double v = ACC[e]; \
      if (v > v0) { v1 = v0; i1 = i0; v0 = v; i0 = e; } \
      else if (v > v1) { v1 = v; i1 = e; } \
    } \
    double ex = exp(v1 - v0); \
    double denom = 1.0 + ex; \
    eidx[N]  = make_int2(i0, i1); \
    pvals[N] = make_float2((float)(1.0 / denom), (float)(ex / denom)); \
  }
  if (lane == 0) TOPSEL(acc0, n0)
  if (lane == 1) TOPSEL(acc1, n0 + 1)
#undef TOPSEL
}

// ---------------- histogram: counts + colsum via LDS bins ----------------
__global__ __launch_bounds__(256) void hist_kernel(
    const int2* __restrict__ eidx, const float2* __restrict__ pvals,
    int* __restrict__ counts, float* __restrict__ colsum)
{
  __shared__ int   cbin[NEXP];
  __shared__ float lbin[NEXP];
  if (threadIdx.x < NEXP) { cbin[threadIdx.x] = 0; lbin[threadIdx.x] = 0.f; }
  __syncthreads();
  int n = blockIdx.x * 256 + threadIdx.x;
  int2 e = eidx[n];
  float2 p = pvals[n];
  atomicAdd(&cbin[e.x], 1);  atomicAdd(&lbin[e.x], p.x);
  atomicAdd(&cbin[e.y], 1);  atomicAdd(&lbin[e.y], p.y);
  __syncthreads();
  if (threadIdx.x < NEXP) {
    atomicAdd(&counts[threadIdx.x], cbin[threadIdx.x]);
    atomicAdd(&colsum[threadIdx.x], lbin[threadIdx.x]);
  }
}

// ---------------- scan bases (128-aligned segments) + loss ----------------
__global__ void scan_loss_kernel(const int* __restrict__ counts, int* __restrict__ base,
                                 const float* __restrict__ colsum, float* __restrict__ loss_out)
{
  if (threadIdx.x == 0 && blockIdx.x == 0) {
    int acc = 0;
    for (int e = 0; e < NEXP; e++) { base[e] = acc; acc += (counts[e] + 127) & ~127; }
    base[NEXP] = acc;
    double s = 0.0;
    for (int e = 0; e < NEXP; e++) { double c = (double)colsum[e]; s += c * c; }
    loss_out[0] = (float)(1.6 * s / ((double)NTOK * (double)NTOK));
  }
}

// ---------------- scatter: wave-aggregated cursor atomics; records slot positions ----------------
__global__ __launch_bounds__(256) void scatter_kernel(
    const int2* __restrict__ eidx, const int* __restrict__ base, int* __restrict__ cursor,
    int* __restrict__ tok, int2* __restrict__ spos)
{
  int n = blockIdx.x * 256 + threadIdx.x;
  int lane = threadIdx.x & 63;
  int2 e = eidx[n];
  int myE[2] = {e.x, e.y};
  int myPos[2];
#pragma unroll
  for (int s = 0; s < 2; s++) {
    int eq = myE[s];
#pragma unroll
    for (int q = 0; q < NEXP; q++) {
      unsigned long long m = __ballot(eq == q);
      if (eq == q) {
        int cnt = __popcll(m);
        int pre = __popcll(m & ((1ull << lane) - 1ull));
        int b = 0;
        if (pre == 0) b = atomicAdd(&cursor[q], cnt);
        int leader = __ffsll((long long)m) - 1;
        b = __shfl(b, leader, 64);
        int pos = base[q] + b + pre;
        tok[pos] = n;
        myPos[s] = pos;
      }
    }
  }
  spos[n] = make_int2(myPos[0], myPos[1]);
}

// ---------------- grouped expert down-proj: bf16 MFMA, 128x128 tile, BK=64, split-K ----------------
// XCD-chunked bijective swizzle (nwg = 8 * cpx exactly): each XCD gets a contiguous run of
// logical block ids. Within a run, out-block varies FASTEST -> the 4 blocks sharing one
// gathered A slot-tile are temporally + XCD adjacent (A hits L2 instead of 4x HBM re-fetch),
// and an expert's B panel stays L2-resident across consecutive slot-groups.
// T3 minimum-2-phase dbuf staging retained from R1.
__global__ __launch_bounds__(256) void down_mfma_kernel(
    const unsigned short* __restrict__ xb, const unsigned short* __restrict__ dwb,
    const int* __restrict__ base, const int* __restrict__ tok,
    unsigned short* __restrict__ seg, int kcount)
{
  __shared__ unsigned short smem[32768];   // 2 x (A[8192] + B[8192]); epilogue overlays 128x136=17408

  // grid is 1-D: DGRID_HALF * ksplit blocks (1152 or 576; both divisible by 8)
  int wg  = blockIdx.x;
  int cpx = gridDim.x >> 3;                 // blocks per XCD chunk
  int logical = (wg & 7) * cpx + (wg >> 3); // bijective XCD chunking
  int kh      = logical / DGRID_HALF;
  int r       = logical % DGRID_HALF;
  int slot0   = (r >> 2) * 128;             // slot-group
  int out0    = (r & 3) * 128;              // out-block fastest (A-tile reuse)

  if (slot0 >= base[NEXP]) return;          // uniform per block
  int e = 0;
#pragma unroll
  for (int q = 1; q < NEXP; q++) if (base[q] <= slot0) e = q;
  int kbase = kh * kcount * 64;

  int tid = threadIdx.x;
  const int l = tid & 63, w = tid >> 6;
  const int wm = w & 1, wn = w >> 1;
  const int lm = l & 15, quad = l >> 4;

  const unsigned short* agp[4];
  const unsigned short* bgp[4];
#pragma unroll
  for (int i = 0; i < 4; i++) {
    int g = w * 4 + i;
    int rr = g * 8 + (l & 7);
    int kc = l >> 3;
    int t = tok[slot0 + rr];
    agp[i] = xb + (size_t)(t < 0 ? 0 : t) * HID + kbase + kc * 8;
    bgp[i] = dwb + ((size_t)e * DWN + out0 + rr) * HID + kbase + kc * 8;
  }

  int am_off[4], bn_off[4];
#pragma unroll
  for (int mi = 0; mi < 4; mi++) {
    int m = wm * 64 + mi * 16 + lm;
    am_off[mi] = (m >> 3) * 512 + (m & 7) * 8 + quad * 64;
    int nn = wn * 64 + mi * 16 + lm;
    bn_off[mi] = (nn >> 3) * 512 + (nn & 7) * 8 + quad * 64;
  }

  f32x4 acc[4][4] = {};

  // prologue: stage K-tile 0 into buffer 0
#pragma unroll
  for (int i = 0; i < 4; i++) {
    int g = w * 4 + i;
    ASYNC16(agp[i], &smem[g * 512]);
    ASYNC16(bgp[i], &smem[8192 + g * 512]);
  }
  __syncthreads();                       // vmcnt(0): buf0 ready

  int cur = 0;
  for (int it = 0; it < kcount; it++) {
    unsigned short* As = smem + cur * 16384;
    unsigned short* Bs = As + 8192;
    // prefetch next K-tile into the other buffer (overlaps with compute below)
    if (it + 1 < kcount) {
      int k0 = (it + 1) * 64;
      unsigned short* Ap = smem + (cur ^ 1) * 16384;
#pragma unroll
      for (int i = 0; i < 4; i++) {
        int g = w * 4 + i;
        ASYNC16(agp[i] + k0, &Ap[g * 512]);
        ASYNC16(bgp[i] + k0, &Ap[8192 + g * 512]);
      }
    }
#pragma unroll
    for (int kk = 0; kk < 2; kk++) {
      bf16x8 af[4], bfr[4];
#pragma unroll
      for (int mi = 0; mi < 4; mi++) af[mi]  = *(const bf16x8*)&As[am_off[mi] + kk * 256];
#pragma unroll
      for (int ni = 0; ni < 4; ni++) bfr[ni] = *(const bf16x8*)&Bs[bn_off[ni] + kk * 256];
#pragma unroll
      for (int mi = 0; mi < 4; mi++)
#pragma unroll
        for (int ni = 0; ni < 4; ni++)
          acc[mi][ni] = __builtin_amdgcn_mfma_f32_16x16x32_bf16(af[mi], bfr[ni], acc[mi][ni], 0, 0, 0);
    }
    __syncthreads();                    // all reads of buf[cur] done; buf[cur^1] loads drained
    cur ^= 1;
  }

  // epilogue: stage bf16 tile in LDS (stride 136 shorts = 272B, 16B-aligned, bank-spread),
  // then fully-coalesced 16B global stores. No atomics. (loop-end barrier already synced)
#pragma unroll
  for (int mi = 0; mi < 4; mi++)
#pragma unroll
    for (int reg = 0; reg < 4; reg++) {
      int m = wm * 64 + mi * 16 + quad * 4 + reg;
#pragma unroll
      for (int ni = 0; ni < 4; ni++) {
        int c = wn * 64 + ni * 16 + lm;
        smem[m * 136 + c] = f2bf(acc[mi][ni][reg]);
      }
    }
  __syncthreads();
#pragma unroll
  for (int it2 = 0; it2 < 8; it2++) {
    int chunk = it2 * 256 + tid;
    int row = chunk >> 4, off = (chunk & 15) * 8;
    uint4 v = *(const uint4*)&smem[row * 136 + off];
    *(uint4*)&seg[(size_t)kh * SEGHALF_SHORTS + (size_t)(slot0 + row) * 512 + out0 + off] = v;
  }
}

// ---------------- combine (gather 2 slots x ksplit halves) + bias + gelu_new -> h bf16 ----------------
__global__ __launch_bounds__(256) void combine_gelu_kernel(
    const unsigned short* __restrict__ seg, const int2* __restrict__ spos,
    const float2* __restrict__ pv, const int2* __restrict__ eix,
    const float* __restrict__ db, unsigned short* __restrict__ h, int ksplit)
{
  int n = blockIdx.x * 4 + (threadIdx.x >> 6);
  int lane = threadIdx.x & 63;
  int c0 = lane * 8;
  int2 sp = spos[n];
  float2 p = pv[n];
  int2 e = eix[n];

  float d0[8] = {0,0,0,0,0,0,0,0}, d1[8] = {0,0,0,0,0,0,0,0};
  for (int hh = 0; hh < ksplit; hh++) {
    uint4 u0 = *(const uint4*)(seg + (size_t)hh * SEGHALF_SHORTS + (size_t)sp.x * 512 + c0);
    uint4 u1 = *(const uint4*)(seg + (size_t)hh * SEGHALF_SHORTS + (size_t)sp.y * 512 + c0);
    const unsigned short* s0 = (const unsigned short*)&u0;
    const unsigned short* s1 = (const unsigned short*)&u1;
#pragma unroll
    for (int j = 0; j < 8; j++) { d0[j] += bf2f(s0[j]); d1[j] += bf2f(s1[j]); }
  }
  float b0[8], b1[8];
  *(float4*)&b0[0] = *(const float4*)(db + e.x * DWN + c0);
  *(float4*)&b0[4] = *(const float4*)(db + e.x * DWN + c0 + 4);
  *(float4*)&b1[0] = *(const float4*)(db + e.y * DWN + c0);
  *(float4*)&b1[4] = *(const float4*)(db + e.y * DWN + c0 + 4);

  unsigned short o[8];
#pragma unroll
  for (int j = 0; j < 8; j++) {
    float xx = p.x * (d0[j] + b0[j]) + p.y * (d1[j] + b1[j]);
    float inner = 0.7978845608028654f * (xx + 0.044715f * xx * xx * xx);
    o[j] = f2bf(0.5f * xx * (1.0f + tanhf(inner)));
  }
  *(uint4*)(h + (size_t)n * DWN + c0) = *(const uint4*)o;
}

// ---------------- up-proj: bf16 MFMA, 128x128 tile, BK=64, K=512, dbuf-prefetch ----------------
// XCD-chunked swizzle (1024 = 8*128): col-block fastest within a chunk -> the 16 blocks
// sharing one h A-tile are XCD+temporally adjacent; uwb (2MB) becomes L2-resident per XCD.
__global__ __launch_bounds__(256) void up_mfma_kernel(
    const unsigned short* __restrict__ h, const unsigned short* __restrict__ uwb,
    const float* __restrict__ ub, float* __restrict__ out)
{
  __shared__ unsigned short smem[32768];   // 2 x (A[8192] + B[8192])

  int wg  = blockIdx.x;                    // grid = 1024
  int cpx = gridDim.x >> 3;                // 128
  int logical = (wg & 7) * cpx + (wg >> 3);
  int row0 = (logical >> 4) * 128;
  int col0 = (logical & 15) * 128;

  int tid = threadIdx.x;
  const int l = tid & 63, w = tid >> 6;
  const int wm = w & 1, wn = w >> 1;
  const int lm = l & 15, quad = l >> 4;

  const unsigned short* agp[4];
  const unsigned short* bgp[4];
#pragma unroll
  for (int i = 0; i < 4; i++) {
    int g = w * 4 + i;
    int rr = g * 8 + (l & 7);
    int kc = l >> 3;
    agp[i] = h   + (size_t)(row0 + rr) * DWN + kc * 8;
    bgp[i] = uwb + (size_t)(col0 + rr) * DWN + kc * 8;
  }

  int am_off[4], bn_off[4];
#pragma unroll
  for (int mi = 0; mi < 4; mi++) {
    int m = wm * 64 + mi * 16 + lm;
    am_off[mi] = (m >> 3) * 512 + (m & 7) * 8 + quad * 64;
    int nn = wn * 64 + mi * 16 + lm;
    bn_off[mi] = (nn >> 3) * 512 + (nn & 7) * 8 + quad * 64;
  }

  f32x4 acc[4][4] = {};

  // prologue: stage K-tile 0 into buffer 0
#pragma unroll
  for (int i = 0; i < 4; i++) {
    int g = w * 4 + i;
    ASYNC16(agp[i], &smem[g * 512]);
    ASYNC16(bgp[i], &smem[8192 + g * 512]);
  }
  __syncthreads();

  int cur = 0;
  for (int k0 = 0; k0 < DWN; k0 += 64) {
    unsigned short* As = smem + cur * 16384;
    unsigned short* Bs = As + 8192;
    if (k0 + 64 < DWN) {
      unsigned short* Ap = smem + (cur ^ 1) * 16384;
#pragma unroll
      for (int i = 0; i < 4; i++) {
        int g = w * 4 + i;
        ASYNC16(agp[i] + k0 + 64, &Ap[g * 512]);
        ASYNC16(bgp[i] + k0 + 64, &Ap[8192 + g * 512]);
      }
    }
#pragma unroll
    for (int kk = 0; kk < 2; kk++) {
      bf16x8 af[4], bfr[4];
#pragma unroll
      for (int mi = 0; mi < 4; mi++) af[mi]  = *(const bf16x8*)&As[am_off[mi] + kk * 256];
#pragma unroll
      for (int ni = 0; ni < 4; ni++) bfr[ni] = *(const bf16x8*)&Bs[bn_off[ni] + kk * 256];
#pragma unroll
      for (int mi = 0; mi < 4; mi++)
#pragma unroll
        for (int ni = 0; ni < 4; ni++)
          acc[mi][ni] = __builtin_amdgcn_mfma_f32_16x16x32_bf16(af[mi], bfr[ni], acc[mi][ni], 0, 0, 0);
    }
    __syncthreads();
    cur ^= 1;
  }

  float ubv[4];
#pragma unroll
  for (int ni = 0; ni < 4; ni++)
    ubv[ni] = ub[col0 + wn * 64 + ni * 16 + lm];
#pragma unroll
  for (int mi = 0; mi < 4; mi++) {
#pragma unroll
    for (int reg = 0; reg < 4; reg++) {
      int m = row0 + wm * 64 + mi * 16 + quad * 4 + reg;
      float* orow = out + (size_t)m * HID;
#pragma unroll
      for (int ni = 0; ni < 4; ni++) {
        int gc = col0 + wn * 64 + ni * 16 + lm;
        orow[gc] = acc[mi][ni][reg] + ubv[ni];
      }
    }
  }
}

extern "C" void kernel_launch(void* const* d_in, const int* in_sizes, int n_in,
                              void* d_out, int out_size, void* d_ws, size_t ws_size,
                              hipStream_t stream)
{
  const float* x  = (const float*)d_in[0];
  const float* gw = (const float*)d_in[1];
  const float* dw = (const float*)d_in[2];
  const float* db = (const float*)d_in[3];
  const float* uw = (const float*)d_in[4];
  const float* ub = (const float*)d_in[5];
  float* out = (float*)d_out;

  char* ws = (char*)d_ws;
  unsigned short* xb   = (unsigned short*)(ws + OFF_XB);
  unsigned short* dwb  = (unsigned short*)(ws + OFF_DWB);
  unsigned short* uwb  = (unsigned short*)(ws + OFF_UWB);
  unsigned short* h    = (unsigned short*)(ws + OFF_H);
  unsigned short* seg  = (unsigned short*)(ws + OFF_SEG);
  int*    tok    = (int*)(ws + OFF_TOK);
  int2*   spos   = (int2*)(ws + OFF_SPOS);
  int2*   eidx   = (int2*)(ws + OFF_EIDX);
  float2* pvals  = (float2*)(ws + OFF_PVAL);
  int*    counts = (int*)(ws + OFF_COUNTS);
  int*    base   = (int*)(ws + OFF_BASE);
  int*    cursor = (int*)(ws + OFF_CURSOR);
  float*  colsum = (float*)(ws + OFF_COLSUM);

  // split-K only if the workspace is big enough (ws_size constant per session -> same work each call)
  const int ksplit = (ws_size >= (size_t)WS_NEED2) ? 2 : 1;
  const int kcount = (HID / 64) / ksplit;

  hipMemsetAsync(tok, 0xFF, PADSLOT * sizeof(int), stream);     // token = -1 padding
  hipMemsetAsync(counts, 0, 320, stream);                        // counts/base/cursor/colsum

  // x cast is fused into gate_kernel (reads x once, writes xb)
  cast8_kernel<<<(NEXP * DWN * HID) / 8 / 256, 256, 0, stream>>>(dw, dwb);
  cast8_kernel<<<(HID * DWN) / 8 / 256, 256, 0, stream>>>(uw, uwb);

  gate_kernel<<<NTOK / 8, 256, 0, stream>>>(x, gw, eidx, pvals, xb);
  hist_kernel<<<NTOK / 256, 256, 0, stream>>>(eidx, pvals, counts, colsum);
  scan_loss_kernel<<<1, 64, 0, stream>>>(counts, base, colsum, out + (size_t)NTOK * HID);
  scatter_kernel<<<NTOK / 256, 256, 0, stream>>>(eidx, base, cursor, tok, spos);

  down_mfma_kernel<<<DGRID_HALF * ksplit, 256, 0, stream>>>(xb, dwb, base, tok, seg, kcount);

  combine_gelu_kernel<<<NTOK / 4, 256, 0, stream>>>(seg, spos, pvals, eidx, db, h, ksplit);

  up_mfma_kernel<<<NTOK / 128 * (HID / 128), 256, 0, stream>>>(h, uwb, ub, out);
}

// Round 4
// 404.598 us; speedup vs baseline: 1.1271x; 1.1200x over previous
//
#include <hip/hip_runtime.h>
#include <hip/hip_bf16.h>
#include <math.h>

// Problem constants
#define NTOK   8192      // B*S
#define HID    2048
#define DWN    512
#define NEXP   16
#define PADSLOT 18432    // 144*128 >= 16384 + 16*127 (segments 128-aligned)
#define NSLOTBLK 144     // PADSLOT/128
#define DGRID_HALF (NSLOTBLK * 4)   // 576 blocks per K-half (slot-blocks x out-blocks)

// ws layout (bytes). H overlays DWB (dwb dead after down_mfma; combine writes h after).
#define OFF_XB       0                       // bf16[NTOK*HID]       = 33554432
#define OFF_DWB      33554432                // bf16[NEXP*DWN*HID]   = 33554432
#define OFF_H        33554432                // bf16[NTOK*DWN]       = 8388608 (overlay on DWB)
#define OFF_UWB      67108864                // bf16[HID*DWN]        = 2097152
#define OFF_TOK      69206016                // int[PADSLOT]         = 73728
#define OFF_SPOS     69279744                // int2[NTOK]           = 65536
#define OFF_EIDX     69345280                // int2[NTOK]           = 65536
#define OFF_PVAL     69410816                // float2[NTOK]         = 65536
#define OFF_COUNTS   69476352                // int[16]
#define OFF_BASE     69476416                // int[17] (padded to 128)
#define OFF_CURSOR   69476544                // int[16]
#define OFF_COLSUM   69476608                // float[16]
#define OFF_SEG      69476672                // bf16[ksplit][PADSLOT*512]
#define SEGHALF_SHORTS 9437184               // PADSLOT*512
#define SEGHALF_BYTES  18874368
#define WS_NEED1     (OFF_SEG + 1 * SEGHALF_BYTES)   //  88.4 MB
#define WS_NEED2     (OFF_SEG + 2 * SEGHALF_BYTES)   // 107.2 MB

typedef __attribute__((ext_vector_type(8))) __bf16 bf16x8;
typedef __attribute__((ext_vector_type(4))) float f32x4;

// async 16B/lane global->LDS copy (LDS dest is wave-uniform base; HW adds lane*16)
#define ASYNC16(gsrc, ldst) \
  __builtin_amdgcn_global_load_lds((const __attribute__((address_space(1))) unsigned int*)(gsrc), \
                                   (__attribute__((address_space(3))) unsigned int*)(ldst), 16, 0, 0)

__device__ inline unsigned short f2bf(float f) {
  unsigned int u = __float_as_uint(f);
  unsigned int r = (u + 0x7FFFu + ((u >> 16) & 1u)) >> 16;
  return (unsigned short)r;
}
__device__ inline float bf2f(unsigned short s) {
  return __uint_as_float((unsigned int)s << 16);
}

// ---------------- fp32 -> bf16 cast, 8 elems/thread ----------------
__global__ __launch_bounds__(256) void cast8_kernel(const float* __restrict__ src,
                                                    unsigned short* __restrict__ dst)
{
  size_t i = ((size_t)blockIdx.x * 256 + threadIdx.x) * 8;
  float4 a = *(const float4*)(src + i);
  float4 b = *(const float4*)(src + i + 4);
  unsigned short o[8];
  o[0]=f2bf(a.x); o[1]=f2bf(a.y); o[2]=f2bf(a.z); o[3]=f2bf(a.w);
  o[4]=f2bf(b.x); o[5]=f2bf(b.y); o[6]=f2bf(b.z); o[7]=f2bf(b.w);
  *(uint4*)(dst + i) = *(const uint4*)o;
}

// ---------------- gating: LDS-staged gate weights, 2 tokens/wave, f64 accumulation ----------
// R3 restructure: the R2 version was L2-latency-bound (VGPR=64 all eaten by f64 accs -> zero
// load ILP). Now gw is staged per-block in 16KB chunks via global_load_lds (consumes NO VGPRs),
// double-buffered; the FMA chain reads from LDS (ds_read_b128, ~12cyc) instead of L2 (~300cyc).
// Numerics BIT-IDENTICAL to the passing R2 kernel: same token map, same d=d0+lane*4 walk,
// same per-lane FMA order, same butterfly reduce + TOPSEL; gw values pass through LDS unchanged.
__global__ __launch_bounds__(256, 4) void gate_kernel(
    const float* __restrict__ x, const float* __restrict__ gw,
    int2* __restrict__ eidx, float2* __restrict__ pvals,
    unsigned short* __restrict__ xbw)
{
  __shared__ float gws[2][NEXP * 256];   // 2 x 16KB double-buffered gw chunk

  int lane = threadIdx.x & 63;
  int wave = threadIdx.x >> 6;
  int n0 = (blockIdx.x * 4 + wave) * 2;          // 2 tokens per wave
  const float* xr0 = x + (size_t)n0 * HID;
  const float* xr1 = xr0 + HID;
  unsigned short* xw0 = xbw + (size_t)n0 * HID;
  unsigned short* xw1 = xw0 + HID;

  double acc0[NEXP], acc1[NEXP];
#pragma unroll
  for (int e = 0; e < NEXP; e++) { acc0[e] = 0.0; acc1[e] = 0.0; }

  // prologue: stage chunk 0 (each wave stages 4 expert rows of 256 floats = 1KB each)
#pragma unroll
  for (int r = 0; r < 4; r++) {
    int e = r * 4 + wave;
    ASYNC16(gw + (size_t)e * HID + lane * 4, &gws[0][e * 256]);
  }
  __syncthreads();                                // vmcnt(0): chunk 0 ready

  int cur = 0;
  for (int c = 0; c < HID / 256; c++) {
    int d0 = c * 256;
    // prefetch next gw chunk into the other buffer (zero-VGPR async)
    if (c + 1 < HID / 256) {
#pragma unroll
      for (int r = 0; r < 4; r++) {
        int e = r * 4 + wave;
        ASYNC16(gw + (size_t)e * HID + d0 + 256 + lane * 4, &gws[cur ^ 1][e * 256]);
      }
    }
    int d = d0 + lane * 4;
    float4 xv0 = *(const float4*)(xr0 + d);
    float4 xv1 = *(const float4*)(xr1 + d);
    unsigned short o0[4] = {f2bf(xv0.x), f2bf(xv0.y), f2bf(xv0.z), f2bf(xv0.w)};
    unsigned short o1[4] = {f2bf(xv1.x), f2bf(xv1.y), f2bf(xv1.z), f2bf(xv1.w)};
    *(uint2*)(xw0 + d) = *(const uint2*)o0;
    *(uint2*)(xw1 + d) = *(const uint2*)o1;
    double x00 = (double)xv0.x, x01 = (double)xv0.y, x02 = (double)xv0.z, x03 = (double)xv0.w;
    double x10 = (double)xv1.x, x11 = (double)xv1.y, x12 = (double)xv1.z, x13 = (double)xv1.w;
    const float* gs = &gws[cur][lane * 4];
#pragma unroll
    for (int e = 0; e < NEXP; e++) {
      float4 g = *(const float4*)(gs + e * 256);
      double g0 = (double)g.x, g1 = (double)g.y, g2 = (double)g.z, g3 = (double)g.w;
      double s0 = acc0[e], s1 = acc1[e];
      s0 = fma(x00, g0, s0); s0 = fma(x01, g1, s0);
      s0 = fma(x02, g2, s0); s0 = fma(x03, g3, s0);
      s1 = fma(x10, g0, s1); s1 = fma(x11, g1, s1);
      s1 = fma(x12, g2, s1); s1 = fma(x13, g3, s1);
      acc0[e] = s0; acc1[e] = s1;
    }
    __syncthreads();                              // chunk consumed; next chunk's loads drained
    cur ^= 1;
  }

  // butterfly reduce across 64 lanes (all lanes end with the totals)
#define RED(v) { v += __shfl_xor(v,32,64); v += __shfl_xor(v,16,64); v += __shfl_xor(v,8,64); \
                 v += __shfl_xor(v,4,64);  v += __shfl_xor(v,2,64);  v += __shfl_xor(v,1,64); }
#pragma unroll
  for (int e = 0; e < NEXP; e++) { RED(acc0[e]) RED(acc1[e]) }
#undef RED

#define TOPSEL(ACC, N) { \
    double v0 = -1e300, v1 = -1e300; int i0 = 0, i1 = 0; \
    _Pragma("unroll") \
    for (int e = 0; e < NEXP; e++) { \
      double v = ACC[e]; \
      if (v > v0) { v1 = v0; i1 = i0; v0 = v; i0 = e; } \
      else if (v > v1) { v1 = v; i1 = e; } \
    } \
    double ex = exp(v1 - v0); \
    double denom = 1.0 + ex; \
    eidx[N]  = make_int2(i0, i1); \
    pvals[N] = make_float2((float)(1.0 / denom), (float)(ex / denom)); \
  }
  if (lane == 0) TOPSEL(acc0, n0)
  if (lane == 1) TOPSEL(acc1, n0 + 1)
#undef TOPSEL
}

// ---------------- histogram: counts + colsum via LDS bins ----------------
__global__ __launch_bounds__(256) void hist_kernel(
    const int2* __restrict__ eidx, const float2* __restrict__ pvals,
    int* __restrict__ counts, float* __restrict__ colsum)
{
  __shared__ int   cbin[NEXP];
  __shared__ float lbin[NEXP];
  if (threadIdx.x < NEXP) { cbin[threadIdx.x] = 0; lbin[threadIdx.x] = 0.f; }
  __syncthreads();
  int n = blockIdx.x * 256 + threadIdx.x;
  int2 e = eidx[n];
  float2 p = pvals[n];
  atomicAdd(&cbin[e.x], 1);  atomicAdd(&lbin[e.x], p.x);
  atomicAdd(&cbin[e.y], 1);  atomicAdd(&lbin[e.y], p.y);
  __syncthreads();
  if (threadIdx.x < NEXP) {
    atomicAdd(&counts[threadIdx.x], cbin[threadIdx.x]);
    atomicAdd(&colsum[threadIdx.x], lbin[threadIdx.x]);
  }
}

// ---------------- scan bases (128-aligned segments) + loss ----------------
__global__ void scan_loss_kernel(const int* __restrict__ counts, int* __restrict__ base,
                                 const float* __restrict__ colsum, float* __restrict__ loss_out)
{
  if (threadIdx.x == 0 && blockIdx.x == 0) {
    int acc = 0;
    for (int e = 0; e < NEXP; e++) { base[e] = acc; acc += (counts[e] + 127) & ~127; }
    base[NEXP] = acc;
    double s = 0.0;
    for (int e = 0; e < NEXP; e++) { double c = (double)colsum[e]; s += c * c; }
    loss_out[0] = (float)(1.6 * s / ((double)NTOK * (double)NTOK));
  }
}

// ---------------- scatter: wave-aggregated cursor atomics; records slot positions ----------------
__global__ __launch_bounds__(256) void scatter_kernel(
    const int2* __restrict__ eidx, const int* __restrict__ base, int* __restrict__ cursor,
    int* __restrict__ tok, int2* __restrict__ spos)
{
  int n = blockIdx.x * 256 + threadIdx.x;
  int lane = threadIdx.x & 63;
  int2 e = eidx[n];
  int myE[2] = {e.x, e.y};
  int myPos[2];
#pragma unroll
  for (int s = 0; s < 2; s++) {
    int eq = myE[s];
#pragma unroll
    for (int q = 0; q < NEXP; q++) {
      unsigned long long m = __ballot(eq == q);
      if (eq == q) {
        int cnt = __popcll(m);
        int pre = __popcll(m & ((1ull << lane) - 1ull));
        int b = 0;
        if (pre == 0) b = atomicAdd(&cursor[q], cnt);
        int leader = __ffsll((long long)m) - 1;
        b = __shfl(b, leader, 64);
        int pos = base[q] + b + pre;
        tok[pos] = n;
        myPos[s] = pos;
      }
    }
  }
  spos[n] = make_int2(myPos[0], myPos[1]);
}

// ---------------- grouped expert down-proj: bf16 MFMA, 128x128 tile, BK=64, split-K ----------------
// XCD-chunked bijective swizzle (nwg = 8 * cpx exactly): each XCD gets a contiguous run of
// logical block ids. Within a run, out-block varies FASTEST -> the 4 blocks sharing one
// gathered A slot-tile are temporally + XCD adjacent (A hits L2 instead of 4x HBM re-fetch),
// and an expert's B panel stays L2-resident across consecutive slot-groups.
// T3 minimum-2-phase dbuf staging retained from R1.
__global__ __launch_bounds__(256) void down_mfma_kernel(
    const unsigned short* __restrict__ xb, const unsigned short* __restrict__ dwb,
    const int* __restrict__ base, const int* __restrict__ tok,
    unsigned short* __restrict__ seg, int kcount)
{
  __shared__ unsigned short smem[32768];   // 2 x (A[8192] + B[8192]); epilogue overlays 128x136=17408

  // grid is 1-D: DGRID_HALF * ksplit blocks (1152 or 576; both divisible by 8)
  int wg  = blockIdx.x;
  int cpx = gridDim.x >> 3;                 // blocks per XCD chunk
  int logical = (wg & 7) * cpx + (wg >> 3); // bijective XCD chunking
  int kh      = logical / DGRID_HALF;
  int r       = logical % DGRID_HALF;
  int slot0   = (r >> 2) * 128;             // slot-group
  int out0    = (r & 3) * 128;              // out-block fastest (A-tile reuse)

  if (slot0 >= base[NEXP]) return;          // uniform per block
  int e = 0;
#pragma unroll
  for (int q = 1; q < NEXP; q++) if (base[q] <= slot0) e = q;
  int kbase = kh * kcount * 64;

  int tid = threadIdx.x;
  const int l = tid & 63, w = tid >> 6;
  const int wm = w & 1, wn = w >> 1;
  const int lm = l & 15, quad = l >> 4;

  const unsigned short* agp[4];
  const unsigned short* bgp[4];
#pragma unroll
  for (int i = 0; i < 4; i++) {
    int g = w * 4 + i;
    int rr = g * 8 + (l & 7);
    int kc = l >> 3;
    int t = tok[slot0 + rr];
    agp[i] = xb + (size_t)(t < 0 ? 0 : t) * HID + kbase + kc * 8;
    bgp[i] = dwb + ((size_t)e * DWN + out0 + rr) * HID + kbase + kc * 8;
  }

  int am_off[4], bn_off[4];
#pragma unroll
  for (int mi = 0; mi < 4; mi++) {
    int m = wm * 64 + mi * 16 + lm;
    am_off[mi] = (m >> 3) * 512 + (m & 7) * 8 + quad * 64;
    int nn = wn * 64 + mi * 16 + lm;
    bn_off[mi] = (nn >> 3) * 512 + (nn & 7) * 8 + quad * 64;
  }

  f32x4 acc[4][4] = {};

  // prologue: stage K-tile 0 into buffer 0
#pragma unroll
  for (int i = 0; i < 4; i++) {
    int g = w * 4 + i;
    ASYNC16(agp[i], &smem[g * 512]);
    ASYNC16(bgp[i], &smem[8192 + g * 512]);
  }
  __syncthreads();                       // vmcnt(0): buf0 ready

  int cur = 0;
  for (int it = 0; it < kcount; it++) {
    unsigned short* As = smem + cur * 16384;
    unsigned short* Bs = As + 8192;
    // prefetch next K-tile into the other buffer (overlaps with compute below)
    if (it + 1 < kcount) {
      int k0 = (it + 1) * 64;
      unsigned short* Ap = smem + (cur ^ 1) * 16384;
#pragma unroll
      for (int i = 0; i < 4; i++) {
        int g = w * 4 + i;
        ASYNC16(agp[i] + k0, &Ap[g * 512]);
        ASYNC16(bgp[i] + k0, &Ap[8192 + g * 512]);
      }
    }
#pragma unroll
    for (int kk = 0; kk < 2; kk++) {
      bf16x8 af[4], bfr[4];
#pragma unroll
      for (int mi = 0; mi < 4; mi++) af[mi]  = *(const bf16x8*)&As[am_off[mi] + kk * 256];
#pragma unroll
      for (int ni = 0; ni < 4; ni++) bfr[ni] = *(const bf16x8*)&Bs[bn_off[ni] + kk * 256];
#pragma unroll
      for (int mi = 0; mi < 4; mi++)
#pragma unroll
        for (int ni = 0; ni < 4; ni++)
          acc[mi][ni] = __builtin_amdgcn_mfma_f32_16x16x32_bf16(af[mi], bfr[ni], acc[mi][ni], 0, 0, 0);
    }
    __syncthreads();                    // all reads of buf[cur] done; buf[cur^1] loads drained
    cur ^= 1;
  }

  // epilogue: stage bf16 tile in LDS (stride 136 shorts = 272B, 16B-aligned, bank-spread),
  // then fully-coalesced 16B global stores. No atomics. (loop-end barrier already synced)
#pragma unroll
  for (int mi = 0; mi < 4; mi++)
#pragma unroll
    for (int reg = 0; reg < 4; reg++) {
      int m = wm * 64 + mi * 16 + quad * 4 + reg;
#pragma unroll
      for (int ni = 0; ni < 4; ni++) {
        int c = wn * 64 + ni * 16 + lm;
        smem[m * 136 + c] = f2bf(acc[mi][ni][reg]);
      }
    }
  __syncthreads();
#pragma unroll
  for (int it2 = 0; it2 < 8; it2++) {
    int chunk = it2 * 256 + tid;
    int row = chunk >> 4, off = (chunk & 15) * 8;
    uint4 v = *(const uint4*)&smem[row * 136 + off];
    *(uint4*)&seg[(size_t)kh * SEGHALF_SHORTS + (size_t)(slot0 + row) * 512 + out0 + off] = v;
  }
}

// ---------------- combine (gather 2 slots x ksplit halves) + bias + gelu_new -> h bf16 ----------------
__global__ __launch_bounds__(256) void combine_gelu_kernel(
    const unsigned short* __restrict__ seg, const int2* __restrict__ spos,
    const float2* __restrict__ pv, const int2* __restrict__ eix,
    const float* __restrict__ db, unsigned short* __restrict__ h, int ksplit)
{
  int n = blockIdx.x * 4 + (threadIdx.x >> 6);
  int lane = threadIdx.x & 63;
  int c0 = lane * 8;
  int2 sp = spos[n];
  float2 p = pv[n];
  int2 e = eix[n];

  float d0[8] = {0,0,0,0,0,0,0,0}, d1[8] = {0,0,0,0,0,0,0,0};
  for (int hh = 0; hh < ksplit; hh++) {
    uint4 u0 = *(const uint4*)(seg + (size_t)hh * SEGHALF_SHORTS + (size_t)sp.x * 512 + c0);
    uint4 u1 = *(const uint4*)(seg + (size_t)hh * SEGHALF_SHORTS + (size_t)sp.y * 512 + c0);
    const unsigned short* s0 = (const unsigned short*)&u0;
    const unsigned short* s1 = (const unsigned short*)&u1;
#pragma unroll
    for (int j = 0; j < 8; j++) { d0[j] += bf2f(s0[j]); d1[j] += bf2f(s1[j]); }
  }
  float b0[8], b1[8];
  *(float4*)&b0[0] = *(const float4*)(db + e.x * DWN + c0);
  *(float4*)&b0[4] = *(const float4*)(db + e.x * DWN + c0 + 4);
  *(float4*)&b1[0] = *(const float4*)(db + e.y * DWN + c0);
  *(float4*)&b1[4] = *(const float4*)(db + e.y * DWN + c0 + 4);

  unsigned short o[8];
#pragma unroll
  for (int j = 0; j < 8; j++) {
    float xx = p.x * (d0[j] + b0[j]) + p.y * (d1[j] + b1[j]);
    float inner = 0.7978845608028654f * (xx + 0.044715f * xx * xx * xx);
    o[j] = f2bf(0.5f * xx * (1.0f + tanhf(inner)));
  }
  *(uint4*)(h + (size_t)n * DWN + c0) = *(const uint4*)o;
}

// ---------------- up-proj: bf16 MFMA, 128x128 tile, BK=64, K=512, dbuf-prefetch ----------------
// XCD-chunked swizzle (1024 = 8*128): col-block fastest within a chunk -> the 16 blocks
// sharing one h A-tile are XCD+temporally adjacent; uwb (2MB) becomes L2-resident per XCD.
__global__ __launch_bounds__(256) void up_mfma_kernel(
    const unsigned short* __restrict__ h, const unsigned short* __restrict__ uwb,
    const float* __restrict__ ub, float* __restrict__ out)
{
  __shared__ unsigned short smem[32768];   // 2 x (A[8192] + B[8192])

  int wg  = blockIdx.x;                    // grid = 1024
  int cpx = gridDim.x >> 3;                // 128
  int logical = (wg & 7) * cpx + (wg >> 3);
  int row0 = (logical >> 4) * 128;
  int col0 = (logical & 15) * 128;

  int tid = threadIdx.x;
  const int l = tid & 63, w = tid >> 6;
  const int wm = w & 1, wn = w >> 1;
  const int lm = l & 15, quad = l >> 4;

  const unsigned short* agp[4];
  const unsigned short* bgp[4];
#pragma unroll
  for (int i = 0; i < 4; i++) {
    int g = w * 4 + i;
    int rr = g * 8 + (l & 7);
    int kc = l >> 3;
    agp[i] = h   + (size_t)(row0 + rr) * DWN + kc * 8;
    bgp[i] = uwb + (size_t)(col0 + rr) * DWN + kc * 8;
  }

  int am_off[4], bn_off[4];
#pragma unroll
  for (int mi = 0; mi < 4; mi++) {
    int m = wm * 64 + mi * 16 + lm;
    am_off[mi] = (m >> 3) * 512 + (m & 7) * 8 + quad * 64;
    int nn = wn * 64 + mi * 16 + lm;
    bn_off[mi] = (nn >> 3) * 512 + (nn & 7) * 8 + quad * 64;
  }

  f32x4 acc[4][4] = {};

  // prologue: stage K-tile 0 into buffer 0
#pragma unroll
  for (int i = 0; i < 4; i++) {
    int g = w * 4 + i;
    ASYNC16(agp[i], &smem[g * 512]);
    ASYNC16(bgp[i], &smem[8192 + g * 512]);
  }
  __syncthreads();

  int cur = 0;
  for (int k0 = 0; k0 < DWN; k0 += 64) {
    unsigned short* As = smem + cur * 16384;
    unsigned short* Bs = As + 8192;
    if (k0 + 64 < DWN) {
      unsigned short* Ap = smem + (cur ^ 1) * 16384;
#pragma unroll
      for (int i = 0; i < 4; i++) {
        int g = w * 4 + i;
        ASYNC16(agp[i] + k0 + 64, &Ap[g * 512]);
        ASYNC16(bgp[i] + k0 + 64, &Ap[8192 + g * 512]);
      }
    }
#pragma unroll
    for (int kk = 0; kk < 2; kk++) {
      bf16x8 af[4], bfr[4];
#pragma unroll
      for (int mi = 0; mi < 4; mi++) af[mi]  = *(const bf16x8*)&As[am_off[mi] + kk * 256];
#pragma unroll
      for (int ni = 0; ni < 4; ni++) bfr[ni] = *(const bf16x8*)&Bs[bn_off[ni] + kk * 256];
#pragma unroll
      for (int mi = 0; mi < 4; mi++)
#pragma unroll
        for (int ni = 0; ni < 4; ni++)
          acc[mi][ni] = __builtin_amdgcn_mfma_f32_16x16x32_bf16(af[mi], bfr[ni], acc[mi][ni], 0, 0, 0);
    }
    __syncthreads();
    cur ^= 1;
  }

  float ubv[4];
#pragma unroll
  for (int ni = 0; ni < 4; ni++)
    ubv[ni] = ub[col0 + wn * 64 + ni * 16 + lm];
#pragma unroll
  for (int mi = 0; mi < 4; mi++) {
#pragma unroll
    for (int reg = 0; reg < 4; reg++) {
      int m = row0 + wm * 64 + mi * 16 + quad * 4 + reg;
      float* orow = out + (size_t)m * HID;
#pragma unroll
      for (int ni = 0; ni < 4; ni++) {
        int gc = col0 + wn * 64 + ni * 16 + lm;
        orow[gc] = acc[mi][ni][reg] + ubv[ni];
      }
    }
  }
}

extern "C" void kernel_launch(void* const* d_in, const int* in_sizes, int n_in,
                              void* d_out, int out_size, void* d_ws, size_t ws_size,
                              hipStream_t stream)
{
  const float* x  = (const float*)d_in[0];
  const float* gw = (const float*)d_in[1];
  const float* dw = (const float*)d_in[2];
  const float* db = (const float*)d_in[3];
  const float* uw = (const float*)d_in[4];
  const float* ub = (const float*)d_in[5];
  float* out = (float*)d_out;

  char* ws = (char*)d_ws;
  unsigned short* xb   = (unsigned short*)(ws + OFF_XB);
  unsigned short* dwb  = (unsigned short*)(ws + OFF_DWB);
  unsigned short* uwb  = (unsigned short*)(ws + OFF_UWB);
  unsigned short* h    = (unsigned short*)(ws + OFF_H);
  unsigned short* seg  = (unsigned short*)(ws + OFF_SEG);
  int*    tok    = (int*)(ws + OFF_TOK);
  int2*   spos   = (int2*)(ws + OFF_SPOS);
  int2*   eidx   = (int2*)(ws + OFF_EIDX);
  float2* pvals  = (float2*)(ws + OFF_PVAL);
  int*    counts = (int*)(ws + OFF_COUNTS);
  int*    base   = (int*)(ws + OFF_BASE);
  int*    cursor = (int*)(ws + OFF_CURSOR);
  float*  colsum = (float*)(ws + OFF_COLSUM);

  // split-K only if the workspace is big enough (ws_size constant per session -> same work each call)
  const int ksplit = (ws_size >= (size_t)WS_NEED2) ? 2 : 1;
  const int kcount = (HID / 64) / ksplit;

  hipMemsetAsync(tok, 0xFF, PADSLOT * sizeof(int), stream);     // token = -1 padding
  hipMemsetAsync(counts, 0, 320, stream);                        // counts/base/cursor/colsum

  // x cast is fused into gate_kernel (reads x once, writes xb)
  cast8_kernel<<<(NEXP * DWN * HID) / 8 / 256, 256, 0, stream>>>(dw, dwb);
  cast8_kernel<<<(HID * DWN) / 8 / 256, 256, 0, stream>>>(uw, uwb);

  gate_kernel<<<NTOK / 8, 256, 0, stream>>>(x, gw, eidx, pvals, xb);
  hist_kernel<<<NTOK / 256, 256, 0, stream>>>(eidx, pvals, counts, colsum);
  scan_loss_kernel<<<1, 64, 0, stream>>>(counts, base, colsum, out + (size_t)NTOK * HID);
  scatter_kernel<<<NTOK / 256, 256, 0, stream>>>(eidx, base, cursor, tok, spos);

  down_mfma_kernel<<<DGRID_HALF * ksplit, 256, 0, stream>>>(xb, dwb, base, tok, seg, kcount);

  combine_gelu_kernel<<<NTOK / 4, 256, 0, stream>>>(seg, spos, pvals, eidx, db, h, ksplit);

  up_mfma_kernel<<<NTOK / 128 * (HID / 128), 256, 0, stream>>>(h, uwb, ub, out);
}

// Round 5
// 394.924 us; speedup vs baseline: 1.1547x; 1.0245x over previous
//
#include <hip/hip_runtime.h>
#include <hip/hip_bf16.h>
#include <math.h>

// Problem constants
#define NTOK   8192      // B*S
#define HID    2048
#define DWN    512
#define NEXP   16
#define PADSLOT 18432    // 144*128 >= 16384 + 16*127 (segments 128-aligned)
#define NSLOTBLK 144     // PADSLOT/128
#define DGRID_HALF (NSLOTBLK * (DWN / 256))   // 288 blocks per K-half (slot-blocks x out-blocks, BN=256)

// ws layout (bytes). H overlays DWB (dwb dead after down_mfma; combine writes h after).
#define OFF_XB       0                       // bf16[NTOK*HID]       = 33554432
#define OFF_DWB      33554432                // bf16[NEXP*DWN*HID]   = 33554432
#define OFF_H        33554432                // bf16[NTOK*DWN]       = 8388608 (overlay on DWB)
#define OFF_UWB      67108864                // bf16[HID*DWN]        = 2097152
#define OFF_TOK      69206016                // int[PADSLOT]         = 73728
#define OFF_SPOS     69279744                // int2[NTOK]           = 65536
#define OFF_EIDX     69345280                // int2[NTOK]           = 65536
#define OFF_PVAL     69410816                // float2[NTOK]         = 65536
#define OFF_COUNTS   69476352                // int[16]
#define OFF_BASE     69476416                // int[17] (padded to 128)
#define OFF_CURSOR   69476544                // int[16]
#define OFF_COLSUM   69476608                // float[16]
#define OFF_SEG      69476672                // bf16[ksplit][PADSLOT*512]
#define SEGHALF_SHORTS 9437184               // PADSLOT*512
#define SEGHALF_BYTES  18874368
#define WS_NEED1     (OFF_SEG + 1 * SEGHALF_BYTES)   //  88.4 MB
#define WS_NEED2     (OFF_SEG + 2 * SEGHALF_BYTES)   // 107.2 MB

typedef __attribute__((ext_vector_type(8))) __bf16 bf16x8;
typedef __attribute__((ext_vector_type(4))) float f32x4;

// async 16B/lane global->LDS copy (LDS dest is wave-uniform base; HW adds lane*16)
#define ASYNC16(gsrc, ldst) \
  __builtin_amdgcn_global_load_lds((const __attribute__((address_space(1))) unsigned int*)(gsrc), \
                                   (__attribute__((address_space(3))) unsigned int*)(ldst), 16, 0, 0)

__device__ inline unsigned short f2bf(float f) {
  unsigned int u = __float_as_uint(f);
  unsigned int r = (u + 0x7FFFu + ((u >> 16) & 1u)) >> 16;
  return (unsigned short)r;
}
__device__ inline float bf2f(unsigned short s) {
  return __uint_as_float((unsigned int)s << 16);
}

// ---------------- fp32 -> bf16 cast, 8 elems/thread ----------------
__global__ __launch_bounds__(256) void cast8_kernel(const float* __restrict__ src,
                                                    unsigned short* __restrict__ dst)
{
  size_t i = ((size_t)blockIdx.x * 256 + threadIdx.x) * 8;
  float4 a = *(const float4*)(src + i);
  float4 b = *(const float4*)(src + i + 4);
  unsigned short o[8];
  o[0]=f2bf(a.x); o[1]=f2bf(a.y); o[2]=f2bf(a.z); o[3]=f2bf(a.w);
  o[4]=f2bf(b.x); o[5]=f2bf(b.y); o[6]=f2bf(b.z); o[7]=f2bf(b.w);
  *(uint4*)(dst + i) = *(const uint4*)o;
}

// ---------------- gating: LDS-staged gate weights, 2 tokens/wave, f64 accumulation ----------
// R3 restructure (passed R4): gw staged per-block in 16KB chunks via global_load_lds (zero VGPR),
// double-buffered; FMA chain reads LDS (~12cyc) instead of L2 (~300cyc). Numerics bit-identical
// to the R2 kernel (same token map, FMA order, reduce, TOPSEL; gw unchanged through LDS).
__global__ __launch_bounds__(256, 4) void gate_kernel(
    const float* __restrict__ x, const float* __restrict__ gw,
    int2* __restrict__ eidx, float2* __restrict__ pvals,
    unsigned short* __restrict__ xbw)
{
  __shared__ float gws[2][NEXP * 256];   // 2 x 16KB double-buffered gw chunk

  int lane = threadIdx.x & 63;
  int wave = threadIdx.x >> 6;
  int n0 = (blockIdx.x * 4 + wave) * 2;          // 2 tokens per wave
  const float* xr0 = x + (size_t)n0 * HID;
  const float* xr1 = xr0 + HID;
  unsigned short* xw0 = xbw + (size_t)n0 * HID;
  unsigned short* xw1 = xw0 + HID;

  double acc0[NEXP], acc1[NEXP];
#pragma unroll
  for (int e = 0; e < NEXP; e++) { acc0[e] = 0.0; acc1[e] = 0.0; }

  // prologue: stage chunk 0 (each wave stages 4 expert rows of 256 floats = 1KB each)
#pragma unroll
  for (int r = 0; r < 4; r++) {
    int e = r * 4 + wave;
    ASYNC16(gw + (size_t)e * HID + lane * 4, &gws[0][e * 256]);
  }
  __syncthreads();                                // vmcnt(0): chunk 0 ready

  int cur = 0;
  for (int c = 0; c < HID / 256; c++) {
    int d0 = c * 256;
    // prefetch next gw chunk into the other buffer (zero-VGPR async)
    if (c + 1 < HID / 256) {
#pragma unroll
      for (int r = 0; r < 4; r++) {
        int e = r * 4 + wave;
        ASYNC16(gw + (size_t)e * HID + d0 + 256 + lane * 4, &gws[cur ^ 1][e * 256]);
      }
    }
    int d = d0 + lane * 4;
    float4 xv0 = *(const float4*)(xr0 + d);
    float4 xv1 = *(const float4*)(xr1 + d);
    unsigned short o0[4] = {f2bf(xv0.x), f2bf(xv0.y), f2bf(xv0.z), f2bf(xv0.w)};
    unsigned short o1[4] = {f2bf(xv1.x), f2bf(xv1.y), f2bf(xv1.z), f2bf(xv1.w)};
    *(uint2*)(xw0 + d) = *(const uint2*)o0;
    *(uint2*)(xw1 + d) = *(const uint2*)o1;
    double x00 = (double)xv0.x, x01 = (double)xv0.y, x02 = (double)xv0.z, x03 = (double)xv0.w;
    double x10 = (double)xv1.x, x11 = (double)xv1.y, x12 = (double)xv1.z, x13 = (double)xv1.w;
    const float* gs = &gws[cur][lane * 4];
#pragma unroll
    for (int e = 0; e < NEXP; e++) {
      float4 g = *(const float4*)(gs + e * 256);
      double g0 = (double)g.x, g1 = (double)g.y, g2 = (double)g.z, g3 = (double)g.w;
      double s0 = acc0[e], s1 = acc1[e];
      s0 = fma(x00, g0, s0); s0 = fma(x01, g1, s0);
      s0 = fma(x02, g2, s0); s0 = fma(x03, g3, s0);
      s1 = fma(x10, g0, s1); s1 = fma(x11, g1, s1);
      s1 = fma(x12, g2, s1); s1 = fma(x13, g3, s1);
      acc0[e] = s0; acc1[e] = s1;
    }
    __syncthreads();                              // chunk consumed; next chunk's loads drained
    cur ^= 1;
  }

  // butterfly reduce across 64 lanes (all lanes end with the totals)
#define RED(v) { v += __shfl_xor(v,32,64); v += __shfl_xor(v,16,64); v += __shfl_xor(v,8,64); \
                 v += __shfl_xor(v,4,64);  v += __shfl_xor(v,2,64);  v += __shfl_xor(v,1,64); }
#pragma unroll
  for (int e = 0; e < NEXP; e++) { RED(acc0[e]) RED(acc1[e]) }
#undef RED

#define TOPSEL(ACC, N) { \
    double v0 = -1e300, v1 = -1e300; int i0 = 0, i1 = 0; \
    _Pragma("unroll") \
    for (int e = 0; e < NEXP; e++) { \
      double v = ACC[e]; \
      if (v > v0) { v1 = v0; i1 = i0; v0 = v; i0 = e; } \
      else if (v > v1) { v1 = v; i1 = e; } \
    } \
    double ex = exp(v1 - v0); \
    double denom = 1.0 + ex; \
    eidx[N]  = make_int2(i0, i1); \
    pvals[N] = make_float2((float)(1.0 / denom), (float)(ex / denom)); \
  }
  if (lane == 0) TOPSEL(acc0, n0)
  if (lane == 1) TOPSEL(acc1, n0 + 1)
#undef TOPSEL
}

// ---------------- histogram: counts + colsum via LDS bins ----------------
__global__ __launch_bounds__(256) void hist_kernel(
    const int2* __restrict__ eidx, const float2* __restrict__ pvals,
    int* __restrict__ counts, float* __restrict__ colsum)
{
  __shared__ int   cbin[NEXP];
  __shared__ float lbin[NEXP];
  if (threadIdx.x < NEXP) { cbin[threadIdx.x] = 0; lbin[threadIdx.x] = 0.f; }
  __syncthreads();
  int n = blockIdx.x * 256 + threadIdx.x;
  int2 e = eidx[n];
  float2 p = pvals[n];
  atomicAdd(&cbin[e.x], 1);  atomicAdd(&lbin[e.x], p.x);
  atomicAdd(&cbin[e.y], 1);  atomicAdd(&lbin[e.y], p.y);
  __syncthreads();
  if (threadIdx.x < NEXP) {
    atomicAdd(&counts[threadIdx.x], cbin[threadIdx.x]);
    atomicAdd(&colsum[threadIdx.x], lbin[threadIdx.x]);
  }
}

// ---------------- scan bases (128-aligned segments) + loss ----------------
__global__ void scan_loss_kernel(const int* __restrict__ counts, int* __restrict__ base,
                                 const float* __restrict__ colsum, float* __restrict__ loss_out)
{
  if (threadIdx.x == 0 && blockIdx.x == 0) {
    int acc = 0;
    for (int e = 0; e < NEXP; e++) { base[e] = acc; acc += (counts[e] + 127) & ~127; }
    base[NEXP] = acc;
    double s = 0.0;
    for (int e = 0; e < NEXP; e++) { double c = (double)colsum[e]; s += c * c; }
    loss_out[0] = (float)(1.6 * s / ((double)NTOK * (double)NTOK));
  }
}

// ---------------- scatter: wave-aggregated cursor atomics; records slot positions ----------------
__global__ __launch_bounds__(256) void scatter_kernel(
    const int2* __restrict__ eidx, const int* __restrict__ base, int* __restrict__ cursor,
    int* __restrict__ tok, int2* __restrict__ spos)
{
  int n = blockIdx.x * 256 + threadIdx.x;
  int lane = threadIdx.x & 63;
  int2 e = eidx[n];
  int myE[2] = {e.x, e.y};
  int myPos[2];
#pragma unroll
  for (int s = 0; s < 2; s++) {
    int eq = myE[s];
#pragma unroll
    for (int q = 0; q < NEXP; q++) {
      unsigned long long m = __ballot(eq == q);
      if (eq == q) {
        int cnt = __popcll(m);
        int pre = __popcll(m & ((1ull << lane) - 1ull));
        int b = 0;
        if (pre == 0) b = atomicAdd(&cursor[q], cnt);
        int leader = __ffsll((long long)m) - 1;
        b = __shfl(b, leader, 64);
        int pos = base[q] + b + pre;
        tok[pos] = n;
        myPos[s] = pos;
      }
    }
  }
  spos[n] = make_int2(myPos[0], myPos[1]);
}

// ---------------- grouped expert down-proj: bf16 MFMA, 128x256 tile, BK=64, 8 waves ----------
// R4 was latency/duty-bound (FETCH halved, time unchanged, MfmaUtil 14%). Parameter-lane fix:
// widen to BN=256 (FLOP/staged-byte 65->87) and 8 waves/block (2M x 4N, per-wave 64x64 --
// inner loop identical to the 4-wave version). BM stays 128: expert segments are 128-aligned,
// a 256-slot block could span two experts. LDS 96KB dbuf. K-accumulation order unchanged ->
// seg bit-identical to R4. XCD-chunked swizzle kept, out-block fastest (A-tile L2 reuse).
__global__ __launch_bounds__(512, 2) void down_mfma_kernel(
    const unsigned short* __restrict__ xb, const unsigned short* __restrict__ dwb,
    const int* __restrict__ base, const int* __restrict__ tok,
    unsigned short* __restrict__ seg, int kcount)
{
  __shared__ unsigned short smem[49152];   // 2 x (A 8192 + B 16384) shorts = 96KB; epi 128x264=67.6KB

  // grid is 1-D: DGRID_HALF * ksplit blocks (576 or 288; both divisible by 8)
  int wg  = blockIdx.x;
  int cpx = gridDim.x >> 3;                 // blocks per XCD chunk
  int logical = (wg & 7) * cpx + (wg >> 3); // bijective XCD chunking
  int kh      = logical / DGRID_HALF;
  int r       = logical % DGRID_HALF;
  int slot0   = (r >> 1) * 128;             // slot-group
  int out0    = (r & 1) * 256;              // out-block fastest (A-tile reuse)

  if (slot0 >= base[NEXP]) return;          // uniform per block
  int e = 0;
#pragma unroll
  for (int q = 1; q < NEXP; q++) if (base[q] <= slot0) e = q;
  int kbase = kh * kcount * 64;

  int tid = threadIdx.x;
  const int l = tid & 63, w = tid >> 6;     // 8 waves
  const int wm = w & 1, wn = w >> 1;        // 2M x 4N
  const int lm = l & 15, quad = l >> 4;

  const unsigned short* agp[2];
  const unsigned short* bgp[4];
#pragma unroll
  for (int i = 0; i < 2; i++) {             // A: 128 rows = 16 groups, 2/wave
    int g = w * 2 + i;
    int rr = g * 8 + (l & 7);
    int kc = l >> 3;
    int t = tok[slot0 + rr];
    agp[i] = xb + (size_t)(t < 0 ? 0 : t) * HID + kbase + kc * 8;
  }
#pragma unroll
  for (int i = 0; i < 4; i++) {             // B: 256 rows = 32 groups, 4/wave
    int g = w * 4 + i;
    int rr = g * 8 + (l & 7);
    int kc = l >> 3;
    bgp[i] = dwb + ((size_t)e * DWN + out0 + rr) * HID + kbase + kc * 8;
  }

  int am_off[4], bn_off[4];
#pragma unroll
  for (int mi = 0; mi < 4; mi++) {
    int m = wm * 64 + mi * 16 + lm;
    am_off[mi] = (m >> 3) * 512 + (m & 7) * 8 + quad * 64;
    int nn = wn * 64 + mi * 16 + lm;
    bn_off[mi] = (nn >> 3) * 512 + (nn & 7) * 8 + quad * 64;
  }

  f32x4 acc[4][4] = {};

  // prologue: stage K-tile 0 into buffer 0
#pragma unroll
  for (int i = 0; i < 2; i++) ASYNC16(agp[i], &smem[(w * 2 + i) * 512]);
#pragma unroll
  for (int i = 0; i < 4; i++) ASYNC16(bgp[i], &smem[8192 + (w * 4 + i) * 512]);
  __syncthreads();                       // vmcnt(0): buf0 ready

  int cur = 0;
  for (int it = 0; it < kcount; it++) {
    unsigned short* As = smem + cur * 24576;
    unsigned short* Bs = As + 8192;
    // prefetch next K-tile into the other buffer (overlaps with compute below)
    if (it + 1 < kcount) {
      int k0 = (it + 1) * 64;
      unsigned short* Ap = smem + (cur ^ 1) * 24576;
#pragma unroll
      for (int i = 0; i < 2; i++) ASYNC16(agp[i] + k0, &Ap[(w * 2 + i) * 512]);
#pragma unroll
      for (int i = 0; i < 4; i++) ASYNC16(bgp[i] + k0, &Ap[8192 + (w * 4 + i) * 512]);
    }
#pragma unroll
    for (int kk = 0; kk < 2; kk++) {
      bf16x8 af[4], bfr[4];
#pragma unroll
      for (int mi = 0; mi < 4; mi++) af[mi]  = *(const bf16x8*)&As[am_off[mi] + kk * 256];
#pragma unroll
      for (int ni = 0; ni < 4; ni++) bfr[ni] = *(const bf16x8*)&Bs[bn_off[ni] + kk * 256];
#pragma unroll
      for (int mi = 0; mi < 4; mi++)
#pragma unroll
        for (int ni = 0; ni < 4; ni++)
          acc[mi][ni] = __builtin_amdgcn_mfma_f32_16x16x32_bf16(af[mi], bfr[ni], acc[mi][ni], 0, 0, 0);
    }
    __syncthreads();                    // all reads of buf[cur] done; buf[cur^1] loads drained
    cur ^= 1;
  }

  // epilogue: stage bf16 tile 128x256 in LDS (stride 264 shorts = 528B, 16B-aligned),
  // then fully-coalesced 16B global stores. No atomics. (loop-end barrier already synced)
#pragma unroll
  for (int mi = 0; mi < 4; mi++)
#pragma unroll
    for (int reg = 0; reg < 4; reg++) {
      int m = wm * 64 + mi * 16 + quad * 4 + reg;
#pragma unroll
      for (int ni = 0; ni < 4; ni++) {
        int c = wn * 64 + ni * 16 + lm;
        smem[m * 264 + c] = f2bf(acc[mi][ni][reg]);
      }
    }
  __syncthreads();
#pragma unroll
  for (int it2 = 0; it2 < 8; it2++) {
    int chunk = it2 * 512 + tid;
    int row = chunk >> 5, off = (chunk & 31) * 8;
    uint4 v = *(const uint4*)&smem[row * 264 + off];
    *(uint4*)&seg[(size_t)kh * SEGHALF_SHORTS + (size_t)(slot0 + row) * 512 + out0 + off] = v;
  }
}

// ---------------- combine (gather 2 slots x ksplit halves) + bias + gelu_new -> h bf16 ----------------
__global__ __launch_bounds__(256) void combine_gelu_kernel(
    const unsigned short* __restrict__ seg, const int2* __restrict__ spos,
    const float2* __restrict__ pv, const int2* __restrict__ eix,
    const float* __restrict__ db, unsigned short* __restrict__ h, int ksplit)
{
  int n = blockIdx.x * 4 + (threadIdx.x >> 6);
  int lane = threadIdx.x & 63;
  int c0 = lane * 8;
  int2 sp = spos[n];
  float2 p = pv[n];
  int2 e = eix[n];

  float d0[8] = {0,0,0,0,0,0,0,0}, d1[8] = {0,0,0,0,0,0,0,0};
  for (int hh = 0; hh < ksplit; hh++) {
    uint4 u0 = *(const uint4*)(seg + (size_t)hh * SEGHALF_SHORTS + (size_t)sp.x * 512 + c0);
    uint4 u1 = *(const uint4*)(seg + (size_t)hh * SEGHALF_SHORTS + (size_t)sp.y * 512 + c0);
    const unsigned short* s0 = (const unsigned short*)&u0;
    const unsigned short* s1 = (const unsigned short*)&u1;
#pragma unroll
    for (int j = 0; j < 8; j++) { d0[j] += bf2f(s0[j]); d1[j] += bf2f(s1[j]); }
  }
  float b0[8], b1[8];
  *(float4*)&b0[0] = *(const float4*)(db + e.x * DWN + c0);
  *(float4*)&b0[4] = *(const float4*)(db + e.x * DWN + c0 + 4);
  *(float4*)&b1[0] = *(const float4*)(db + e.y * DWN + c0);
  *(float4*)&b1[4] = *(const float4*)(db + e.y * DWN + c0 + 4);

  unsigned short o[8];
#pragma unroll
  for (int j = 0; j < 8; j++) {
    float xx = p.x * (d0[j] + b0[j]) + p.y * (d1[j] + b1[j]);
    float inner = 0.7978845608028654f * (xx + 0.044715f * xx * xx * xx);
    o[j] = f2bf(0.5f * xx * (1.0f + tanhf(inner)));
  }
  *(uint4*)(h + (size_t)n * DWN + c0) = *(const uint4*)o;
}

// ---------------- up-proj: bf16 MFMA, 256x256 tile, BK=64, K=512, 8 waves, dbuf-prefetch ----
// Grid = 32x8 = 256 blocks = exactly 1/CU (zero tail). Per-wave 128x64 (acc[8][4]). LDS 128KB.
// FLOP/staged-byte 131 (vs 65 at 128^2). XCD swizzle: col-block fastest (uwb L2-resident).
// K-accumulation order unchanged -> out bit-identical to R4.
__global__ __launch_bounds__(512, 2) void up_mfma_kernel(
    const unsigned short* __restrict__ h, const unsigned short* __restrict__ uwb,
    const float* __restrict__ ub, float* __restrict__ out)
{
  __shared__ unsigned short smem[65536];   // 2 x (A 16384 + B 16384) shorts = 128KB

  int wg  = blockIdx.x;                    // grid = 256
  int cpx = gridDim.x >> 3;                // 32
  int logical = (wg & 7) * cpx + (wg >> 3);
  int row0 = (logical >> 3) * 256;
  int col0 = (logical & 7) * 256;          // col fastest

  int tid = threadIdx.x;
  const int l = tid & 63, w = tid >> 6;    // 8 waves
  const int wm = w & 1, wn = w >> 1;       // 2M x 4N
  const int lm = l & 15, quad = l >> 4;

  const unsigned short* agp[4];
  const unsigned short* bgp[4];
#pragma unroll
  for (int i = 0; i < 4; i++) {            // A,B: 256 rows = 32 groups, 4/wave each
    int g = w * 4 + i;
    int rr = g * 8 + (l & 7);
    int kc = l >> 3;
    agp[i] = h   + (size_t)(row0 + rr) * DWN + kc * 8;
    bgp[i] = uwb + (size_t)(col0 + rr) * DWN + kc * 8;
  }

  int am_off[8], bn_off[4];
#pragma unroll
  for (int mi = 0; mi < 8; mi++) {
    int m = wm * 128 + mi * 16 + lm;
    am_off[mi] = (m >> 3) * 512 + (m & 7) * 8 + quad * 64;
  }
#pragma unroll
  for (int ni = 0; ni < 4; ni++) {
    int nn = wn * 64 + ni * 16 + lm;
    bn_off[ni] = (nn >> 3) * 512 + (nn & 7) * 8 + quad * 64;
  }

  f32x4 acc[8][4] = {};

  // prologue: stage K-tile 0 into buffer 0
#pragma unroll
  for (int i = 0; i < 4; i++) {
    int g = w * 4 + i;
    ASYNC16(agp[i], &smem[g * 512]);
    ASYNC16(bgp[i], &smem[16384 + g * 512]);
  }
  __syncthreads();

  int cur = 0;
  for (int k0 = 0; k0 < DWN; k0 += 64) {
    unsigned short* As = smem + cur * 32768;
    unsigned short* Bs = As + 16384;
    if (k0 + 64 < DWN) {
      unsigned short* Ap = smem + (cur ^ 1) * 32768;
#pragma unroll
      for (int i = 0; i < 4; i++) {
        int g = w * 4 + i;
        ASYNC16(agp[i] + k0 + 64, &Ap[g * 512]);
        ASYNC16(bgp[i] + k0 + 64, &Ap[16384 + g * 512]);
      }
    }
#pragma unroll
    for (int kk = 0; kk < 2; kk++) {
      bf16x8 af[8], bfr[4];
#pragma unroll
      for (int mi = 0; mi < 8; mi++) af[mi]  = *(const bf16x8*)&As[am_off[mi] + kk * 256];
#pragma unroll
      for (int ni = 0; ni < 4; ni++) bfr[ni] = *(const bf16x8*)&Bs[bn_off[ni] + kk * 256];
#pragma unroll
      for (int mi = 0; mi < 8; mi++)
#pragma unroll
        for (int ni = 0; ni < 4; ni++)
          acc[mi][ni] = __builtin_amdgcn_mfma_f32_16x16x32_bf16(af[mi], bfr[ni], acc[mi][ni], 0, 0, 0);
    }
    __syncthreads();
    cur ^= 1;
  }

  float ubv[4];
#pragma unroll
  for (int ni = 0; ni < 4; ni++)
    ubv[ni] = ub[col0 + wn * 64 + ni * 16 + lm];
#pragma unroll
  for (int mi = 0; mi < 8; mi++) {
#pragma unroll
    for (int reg = 0; reg < 4; reg++) {
      int m = row0 + wm * 128 + mi * 16 + quad * 4 + reg;
      float* orow = out + (size_t)m * HID;
#pragma unroll
      for (int ni = 0; ni < 4; ni++) {
        int gc = col0 + wn * 64 + ni * 16 + lm;
        orow[gc] = acc[mi][ni][reg] + ubv[ni];
      }
    }
  }
}

extern "C" void kernel_launch(void* const* d_in, const int* in_sizes, int n_in,
                              void* d_out, int out_size, void* d_ws, size_t ws_size,
                              hipStream_t stream)
{
  const float* x  = (const float*)d_in[0];
  const float* gw = (const float*)d_in[1];
  const float* dw = (const float*)d_in[2];
  const float* db = (const float*)d_in[3];
  const float* uw = (const float*)d_in[4];
  const float* ub = (const float*)d_in[5];
  float* out = (float*)d_out;

  char* ws = (char*)d_ws;
  unsigned short* xb   = (unsigned short*)(ws + OFF_XB);
  unsigned short* dwb  = (unsigned short*)(ws + OFF_DWB);
  unsigned short* uwb  = (unsigned short*)(ws + OFF_UWB);
  unsigned short* h    = (unsigned short*)(ws + OFF_H);
  unsigned short* seg  = (unsigned short*)(ws + OFF_SEG);
  int*    tok    = (int*)(ws + OFF_TOK);
  int2*   spos   = (int2*)(ws + OFF_SPOS);
  int2*   eidx   = (int2*)(ws + OFF_EIDX);
  float2* pvals  = (float2*)(ws + OFF_PVAL);
  int*    counts = (int*)(ws + OFF_COUNTS);
  int*    base   = (int*)(ws + OFF_BASE);
  int*    cursor = (int*)(ws + OFF_CURSOR);
  float*  colsum = (float*)(ws + OFF_COLSUM);

  // split-K only if the workspace is big enough (ws_size constant per session -> same work each call)
  const int ksplit = (ws_size >= (size_t)WS_NEED2) ? 2 : 1;
  const int kcount = (HID / 64) / ksplit;

  hipMemsetAsync(tok, 0xFF, PADSLOT * sizeof(int), stream);     // token = -1 padding
  hipMemsetAsync(counts, 0, 320, stream);                        // counts/base/cursor/colsum

  // x cast is fused into gate_kernel (reads x once, writes xb)
  cast8_kernel<<<(NEXP * DWN * HID) / 8 / 256, 256, 0, stream>>>(dw, dwb);
  cast8_kernel<<<(HID * DWN) / 8 / 256, 256, 0, stream>>>(uw, uwb);

  gate_kernel<<<NTOK / 8, 256, 0, stream>>>(x, gw, eidx, pvals, xb);
  hist_kernel<<<NTOK / 256, 256, 0, stream>>>(eidx, pvals, counts, colsum);
  scan_loss_kernel<<<1, 64, 0, stream>>>(counts, base, colsum, out + (size_t)NTOK * HID);
  scatter_kernel<<<NTOK / 256, 256, 0, stream>>>(eidx, base, cursor, tok, spos);

  down_mfma_kernel<<<DGRID_HALF * ksplit, 512, 0, stream>>>(xb, dwb, base, tok, seg, kcount);

  combine_gelu_kernel<<<NTOK / 4, 256, 0, stream>>>(seg, spos, pvals, eidx, db, h, ksplit);

  up_mfma_kernel<<<(NTOK / 256) * (HID / 256), 512, 0, stream>>>(h, uwb, ub, out);
}

// Round 6
// 374.243 us; speedup vs baseline: 1.2185x; 1.0553x over previous
//
#include <hip/hip_runtime.h>
#include <hip/hip_bf16.h>
#include <math.h>

// Problem constants
#define NTOK   8192      // B*S
#define HID    2048
#define DWN    512
#define NEXP   16
#define PADSLOT 18432    // 144*128 >= 16384 + 16*127 (segments 128-aligned)
#define NSLOTBLK 144     // PADSLOT/128
#define DGRID_HALF (NSLOTBLK * (DWN / 256))   // 288 blocks per K-half (slot-blocks x out-blocks, BN=256)

// ws layout (bytes). H overlays DWB (dwb dead after down_mfma; combine writes h after).
#define OFF_XB       0                       // bf16[NTOK*HID]       = 33554432
#define OFF_DWB      33554432                // bf16[NEXP*DWN*HID]   = 33554432
#define OFF_H        33554432                // bf16[NTOK*DWN]       = 8388608 (overlay on DWB)
#define OFF_UWB      67108864                // bf16[HID*DWN]        = 2097152
#define OFF_TOK      69206016                // int[PADSLOT]         = 73728
#define OFF_SPOS     69279744                // int2[NTOK]           = 65536
#define OFF_EIDX     69345280                // int2[NTOK]           = 65536
#define OFF_PVAL     69410816                // float2[NTOK]         = 65536
#define OFF_COUNTS   69476352                // int[16]
#define OFF_BASE     69476416                // int[17] (padded to 128)
#define OFF_CURSOR   69476544                // int[16]
#define OFF_COLSUM   69476608                // float[16]
#define OFF_SEG      69476672                // bf16[ksplit][PADSLOT*512]
#define SEGHALF_SHORTS 9437184               // PADSLOT*512
#define SEGHALF_BYTES  18874368
#define WS_NEED1     (OFF_SEG + 1 * SEGHALF_BYTES)   //  88.4 MB
#define WS_NEED2     (OFF_SEG + 2 * SEGHALF_BYTES)   // 107.2 MB

typedef __attribute__((ext_vector_type(8))) __bf16 bf16x8;
typedef __attribute__((ext_vector_type(4))) float f32x4;

// async 16B/lane global->LDS copy (LDS dest is wave-uniform base; HW adds lane*16)
#define ASYNC16(gsrc, ldst) \
  __builtin_amdgcn_global_load_lds((const __attribute__((address_space(1))) unsigned int*)(gsrc), \
                                   (__attribute__((address_space(3))) unsigned int*)(ldst), 16, 0, 0)

// counted-vmcnt wait + barrier (T4): N = loads still allowed in flight
#define VMWAIT_BAR(N) do { asm volatile("s_waitcnt vmcnt(" #N ")" ::: "memory"); \
                           __builtin_amdgcn_s_barrier(); } while (0)
#define NOSTMT ((void)0)

__device__ inline unsigned short f2bf(float f) {
  unsigned int u = __float_as_uint(f);
  unsigned int r = (u + 0x7FFFu + ((u >> 16) & 1u)) >> 16;
  return (unsigned short)r;
}
__device__ inline float bf2f(unsigned short s) {
  return __uint_as_float((unsigned int)s << 16);
}

// ---------------- fp32 -> bf16 cast, 8 elems/thread ----------------
__global__ __launch_bounds__(256) void cast8_kernel(const float* __restrict__ src,
                                                    unsigned short* __restrict__ dst)
{
  size_t i = ((size_t)blockIdx.x * 256 + threadIdx.x) * 8;
  float4 a = *(const float4*)(src + i);
  float4 b = *(const float4*)(src + i + 4);
  unsigned short o[8];
  o[0]=f2bf(a.x); o[1]=f2bf(a.y); o[2]=f2bf(a.z); o[3]=f2bf(a.w);
  o[4]=f2bf(b.x); o[5]=f2bf(b.y); o[6]=f2bf(b.z); o[7]=f2bf(b.w);
  *(uint4*)(dst + i) = *(const uint4*)o;
}

// ---------------- gating: LDS-staged gate weights, 2 tokens/wave, f64 accumulation ----------
// (passed R4/R5; unchanged) gw staged per-block in 16KB chunks via global_load_lds (zero VGPR),
// double-buffered; FMA chain reads LDS instead of L2. Numerics bit-identical to R2 kernel.
__global__ __launch_bounds__(256, 4) void gate_kernel(
    const float* __restrict__ x, const float* __restrict__ gw,
    int2* __restrict__ eidx, float2* __restrict__ pvals,
    unsigned short* __restrict__ xbw)
{
  __shared__ float gws[2][NEXP * 256];   // 2 x 16KB double-buffered gw chunk

  int lane = threadIdx.x & 63;
  int wave = threadIdx.x >> 6;
  int n0 = (blockIdx.x * 4 + wave) * 2;          // 2 tokens per wave
  const float* xr0 = x + (size_t)n0 * HID;
  const float* xr1 = xr0 + HID;
  unsigned short* xw0 = xbw + (size_t)n0 * HID;
  unsigned short* xw1 = xw0 + HID;

  double acc0[NEXP], acc1[NEXP];
#pragma unroll
  for (int e = 0; e < NEXP; e++) { acc0[e] = 0.0; acc1[e] = 0.0; }

  // prologue: stage chunk 0 (each wave stages 4 expert rows of 256 floats = 1KB each)
#pragma unroll
  for (int r = 0; r < 4; r++) {
    int e = r * 4 + wave;
    ASYNC16(gw + (size_t)e * HID + lane * 4, &gws[0][e * 256]);
  }
  __syncthreads();                                // vmcnt(0): chunk 0 ready

  int cur = 0;
  for (int c = 0; c < HID / 256; c++) {
    int d0 = c * 256;
    // prefetch next gw chunk into the other buffer (zero-VGPR async)
    if (c + 1 < HID / 256) {
#pragma unroll
      for (int r = 0; r < 4; r++) {
        int e = r * 4 + wave;
        ASYNC16(gw + (size_t)e * HID + d0 + 256 + lane * 4, &gws[cur ^ 1][e * 256]);
      }
    }
    int d = d0 + lane * 4;
    float4 xv0 = *(const float4*)(xr0 + d);
    float4 xv1 = *(const float4*)(xr1 + d);
    unsigned short o0[4] = {f2bf(xv0.x), f2bf(xv0.y), f2bf(xv0.z), f2bf(xv0.w)};
    unsigned short o1[4] = {f2bf(xv1.x), f2bf(xv1.y), f2bf(xv1.z), f2bf(xv1.w)};
    *(uint2*)(xw0 + d) = *(const uint2*)o0;
    *(uint2*)(xw1 + d) = *(const uint2*)o1;
    double x00 = (double)xv0.x, x01 = (double)xv0.y, x02 = (double)xv0.z, x03 = (double)xv0.w;
    double x10 = (double)xv1.x, x11 = (double)xv1.y, x12 = (double)xv1.z, x13 = (double)xv1.w;
    const float* gs = &gws[cur][lane * 4];
#pragma unroll
    for (int e = 0; e < NEXP; e++) {
      float4 g = *(const float4*)(gs + e * 256);
      double g0 = (double)g.x, g1 = (double)g.y, g2 = (double)g.z, g3 = (double)g.w;
      double s0 = acc0[e], s1 = acc1[e];
      s0 = fma(x00, g0, s0); s0 = fma(x01, g1, s0);
      s0 = fma(x02, g2, s0); s0 = fma(x03, g3, s0);
      s1 = fma(x10, g0, s1); s1 = fma(x11, g1, s1);
      s1 = fma(x12, g2, s1); s1 = fma(x13, g3, s1);
      acc0[e] = s0; acc1[e] = s1;
    }
    __syncthreads();                              // chunk consumed; next chunk's loads drained
    cur ^= 1;
  }

  // butterfly reduce across 64 lanes (all lanes end with the totals)
#define RED(v) { v += __shfl_xor(v,32,64); v += __shfl_xor(v,16,64); v += __shfl_xor(v,8,64); \
                 v += __shfl_xor(v,4,64);  v += __shfl_xor(v,2,64);  v += __shfl_xor(v,1,64); }
#pragma unroll
  for (int e = 0; e < NEXP; e++) { RED(acc0[e]) RED(acc1[e]) }
#undef RED

#define TOPSEL(ACC, N) { \
    double v0 = -1e300, v1 = -1e300; int i0 = 0, i1 = 0; \
    _Pragma("unroll") \
    for (int e = 0; e < NEXP; e++) { \
      double v = ACC[e]; \
      if (v > v0) { v1 = v0; i1 = i0; v0 = v; i0 = e; } \
      else if (v > v1) { v1 = v; i1 = e; } \
    } \
    double ex = exp(v1 - v0); \
    double denom = 1.0 + ex; \
    eidx[N]  = make_int2(i0, i1); \
    pvals[N] = make_float2((float)(1.0 / denom), (float)(ex / denom)); \
  }
  if (lane == 0) TOPSEL(acc0, n0)
  if (lane == 1) TOPSEL(acc1, n0 + 1)
#undef TOPSEL
}

// ---------------- histogram: counts + colsum via LDS bins ----------------
__global__ __launch_bounds__(256) void hist_kernel(
    const int2* __restrict__ eidx, const float2* __restrict__ pvals,
    int* __restrict__ counts, float* __restrict__ colsum)
{
  __shared__ int   cbin[NEXP];
  __shared__ float lbin[NEXP];
  if (threadIdx.x < NEXP) { cbin[threadIdx.x] = 0; lbin[threadIdx.x] = 0.f; }
  __syncthreads();
  int n = blockIdx.x * 256 + threadIdx.x;
  int2 e = eidx[n];
  float2 p = pvals[n];
  atomicAdd(&cbin[e.x], 1);  atomicAdd(&lbin[e.x], p.x);
  atomicAdd(&cbin[e.y], 1);  atomicAdd(&lbin[e.y], p.y);
  __syncthreads();
  if (threadIdx.x < NEXP) {
    atomicAdd(&counts[threadIdx.x], cbin[threadIdx.x]);
    atomicAdd(&colsum[threadIdx.x], lbin[threadIdx.x]);
  }
}

// ---------------- scan bases (128-aligned segments) + loss ----------------
__global__ void scan_loss_kernel(const int* __restrict__ counts, int* __restrict__ base,
                                 const float* __restrict__ colsum, float* __restrict__ loss_out)
{
  if (threadIdx.x == 0 && blockIdx.x == 0) {
    int acc = 0;
    for (int e = 0; e < NEXP; e++) { base[e] = acc; acc += (counts[e] + 127) & ~127; }
    base[NEXP] = acc;
    double s = 0.0;
    for (int e = 0; e < NEXP; e++) { double c = (double)colsum[e]; s += c * c; }
    loss_out[0] = (float)(1.6 * s / ((double)NTOK * (double)NTOK));
  }
}

// ---------------- scatter: wave-aggregated cursor atomics; records slot positions ----------------
__global__ __launch_bounds__(256) void scatter_kernel(
    const int2* __restrict__ eidx, const int* __restrict__ base, int* __restrict__ cursor,
    int* __restrict__ tok, int2* __restrict__ spos)
{
  int n = blockIdx.x * 256 + threadIdx.x;
  int lane = threadIdx.x & 63;
  int2 e = eidx[n];
  int myE[2] = {e.x, e.y};
  int myPos[2];
#pragma unroll
  for (int s = 0; s < 2; s++) {
    int eq = myE[s];
#pragma unroll
    for (int q = 0; q < NEXP; q++) {
      unsigned long long m = __ballot(eq == q);
      if (eq == q) {
        int cnt = __popcll(m);
        int pre = __popcll(m & ((1ull << lane) - 1ull));
        int b = 0;
        if (pre == 0) b = atomicAdd(&cursor[q], cnt);
        int leader = __ffsll((long long)m) - 1;
        b = __shfl(b, leader, 64);
        int pos = base[q] + b + pre;
        tok[pos] = n;
        myPos[s] = pos;
      }
    }
  }
  spos[n] = make_int2(myPos[0], myPos[1]);
}

// ---------------- grouped expert down-proj: bf16 MFMA, 128x256, BK=64, 8 waves ----------------
// R5 schedule-lane rewrite (T3+T4+T5): counted-vmcnt depth-2 pipeline. Each wave issues 6
// global_load_lds per K-tile; steady-state 12 outstanding; vmcnt(6) waits only for the OLDER
// tile -- loads stay in flight across barriers (never drain to 0 in the main loop).
// Per tile: read kk0 frags -> MFMA kk0 -> read kk1 frags -> lgkmcnt(0)+s_barrier (buffer free)
// -> STAGE t+2 into freed buffer -> MFMA kk1 -> vmcnt(6)+s_barrier. FMA order per acc element
// unchanged (kk0 then kk1) -> seg bit-identical. XCD-chunked swizzle kept.
__global__ __launch_bounds__(512, 2) void down_mfma_kernel(
    const unsigned short* __restrict__ xb, const unsigned short* __restrict__ dwb,
    const int* __restrict__ base, const int* __restrict__ tok,
    unsigned short* __restrict__ seg, int kcount)
{
  __shared__ unsigned short smem[49152];   // 2 x (A 8192 + B 16384) shorts = 96KB; epi 128x264

  int wg  = blockIdx.x;
  int cpx = gridDim.x >> 3;                 // blocks per XCD chunk
  int logical = (wg & 7) * cpx + (wg >> 3); // bijective XCD chunking
  int kh      = logical / DGRID_HALF;
  int r       = logical % DGRID_HALF;
  int slot0   = (r >> 1) * 128;             // slot-group
  int out0    = (r & 1) * 256;              // out-block fastest (A-tile reuse)

  if (slot0 >= base[NEXP]) return;          // uniform per block
  int e = 0;
#pragma unroll
  for (int q = 1; q < NEXP; q++) if (base[q] <= slot0) e = q;
  int kbase = kh * kcount * 64;

  int tid = threadIdx.x;
  const int l = tid & 63, w = tid >> 6;     // 8 waves
  const int wm = w & 1, wn = w >> 1;        // 2M x 4N
  const int lm = l & 15, quad = l >> 4;

  const unsigned short* agp[2];
  const unsigned short* bgp[4];
#pragma unroll
  for (int i = 0; i < 2; i++) {             // A: 128 rows = 16 groups, 2/wave
    int g = w * 2 + i;
    int rr = g * 8 + (l & 7);
    int kc = l >> 3;
    int t = tok[slot0 + rr];
    agp[i] = xb + (size_t)(t < 0 ? 0 : t) * HID + kbase + kc * 8;
  }
#pragma unroll
  for (int i = 0; i < 4; i++) {             // B: 256 rows = 32 groups, 4/wave
    int g = w * 4 + i;
    int rr = g * 8 + (l & 7);
    int kc = l >> 3;
    bgp[i] = dwb + ((size_t)e * DWN + out0 + rr) * HID + kbase + kc * 8;
  }

  int am_off[4], bn_off[4];
#pragma unroll
  for (int mi = 0; mi < 4; mi++) {
    int m = wm * 64 + mi * 16 + lm;
    am_off[mi] = (m >> 3) * 512 + (m & 7) * 8 + quad * 64;
    int nn = wn * 64 + mi * 16 + lm;
    bn_off[mi] = (nn >> 3) * 512 + (nn & 7) * 8 + quad * 64;
  }

  f32x4 acc[4][4] = {};

  // stage tile T into buffer BUF (6 loads/wave)
#define DSTAGE(BUF, T) do {                                                   \
    int k0_ = (T) * 64;                                                       \
    unsigned short* Ap_ = smem + (BUF) * 24576;                               \
    _Pragma("unroll") for (int i = 0; i < 2; i++)                             \
      ASYNC16(agp[i] + k0_, &Ap_[(w * 2 + i) * 512]);                         \
    _Pragma("unroll") for (int i = 0; i < 4; i++)                             \
      ASYNC16(bgp[i] + k0_, &Ap_[8192 + (w * 4 + i) * 512]);                  \
  } while (0)

  // prologue: tiles 0 and 1 in flight; wait for tile 0 only (vmcnt<=6)
  DSTAGE(0, 0);
  DSTAGE(1, 1);
  asm volatile("s_waitcnt vmcnt(6)" ::: "memory");
  __builtin_amdgcn_s_barrier();

  int cur = 0;
#define DTILE(STAGE_STMT, WAIT_STMT) do {                                     \
    unsigned short* As = smem + cur * 24576;                                  \
    unsigned short* Bs = As + 8192;                                           \
    bf16x8 a0[4], b0[4], a1[4], b1[4];                                        \
    _Pragma("unroll") for (int mi = 0; mi < 4; mi++) {                        \
      a0[mi] = *(const bf16x8*)&As[am_off[mi]];                               \
      b0[mi] = *(const bf16x8*)&Bs[bn_off[mi]];                               \
    }                                                                         \
    __builtin_amdgcn_s_setprio(1);                                            \
    _Pragma("unroll") for (int mi = 0; mi < 4; mi++)                          \
      _Pragma("unroll") for (int ni = 0; ni < 4; ni++)                        \
        acc[mi][ni] = __builtin_amdgcn_mfma_f32_16x16x32_bf16(a0[mi], b0[ni], acc[mi][ni], 0, 0, 0); \
    __builtin_amdgcn_s_setprio(0);                                            \
    _Pragma("unroll") for (int mi = 0; mi < 4; mi++) {                        \
      a1[mi] = *(const bf16x8*)&As[am_off[mi] + 256];                         \
      b1[mi] = *(const bf16x8*)&Bs[bn_off[mi] + 256];                         \
    }                                                                         \
    asm volatile("s_waitcnt lgkmcnt(0)" ::: "memory");                        \
    __builtin_amdgcn_sched_barrier(0);                                        \
    __builtin_amdgcn_s_barrier();          /* all waves done reading buf[cur] */ \
    STAGE_STMT;                                                               \
    __builtin_amdgcn_s_setprio(1);                                            \
    _Pragma("unroll") for (int mi = 0; mi < 4; mi++)                          \
      _Pragma("unroll") for (int ni = 0; ni < 4; ni++)                        \
        acc[mi][ni] = __builtin_amdgcn_mfma_f32_16x16x32_bf16(a1[mi], b1[ni], acc[mi][ni], 0, 0, 0); \
    __builtin_amdgcn_s_setprio(0);                                            \
    WAIT_STMT;                                                                \
  } while (0)

  for (int it = 0; it < kcount - 2; ++it) {
    DTILE(DSTAGE(cur, it + 2), VMWAIT_BAR(6));
    cur ^= 1;
  }
  DTILE(NOSTMT, VMWAIT_BAR(0));   // tile kcount-2: drain last tile's loads
  cur ^= 1;
  DTILE(NOSTMT, NOSTMT);          // tile kcount-1
#undef DTILE
#undef DSTAGE

  // epilogue: stage bf16 tile 128x256 in LDS (stride 264 shorts, 16B-aligned), coalesced stores.
  __syncthreads();
#pragma unroll
  for (int mi = 0; mi < 4; mi++)
#pragma unroll
    for (int reg = 0; reg < 4; reg++) {
      int m = wm * 64 + mi * 16 + quad * 4 + reg;
#pragma unroll
      for (int ni = 0; ni < 4; ni++) {
        int c = wn * 64 + ni * 16 + lm;
        smem[m * 264 + c] = f2bf(acc[mi][ni][reg]);
      }
    }
  __syncthreads();
#pragma unroll
  for (int it2 = 0; it2 < 8; it2++) {
    int chunk = it2 * 512 + tid;
    int row = chunk >> 5, off = (chunk & 31) * 8;
    uint4 v = *(const uint4*)&smem[row * 264 + off];
    *(uint4*)&seg[(size_t)kh * SEGHALF_SHORTS + (size_t)(slot0 + row) * 512 + out0 + off] = v;
  }
}

// ---------------- combine (gather 2 slots x ksplit halves) + bias + gelu_new -> h bf16 ----------------
__global__ __launch_bounds__(256) void combine_gelu_kernel(
    const unsigned short* __restrict__ seg, const int2* __restrict__ spos,
    const float2* __restrict__ pv, const int2* __restrict__ eix,
    const float* __restrict__ db, unsigned short* __restrict__ h, int ksplit)
{
  int n = blockIdx.x * 4 + (threadIdx.x >> 6);
  int lane = threadIdx.x & 63;
  int c0 = lane * 8;
  int2 sp = spos[n];
  float2 p = pv[n];
  int2 e = eix[n];

  float d0[8] = {0,0,0,0,0,0,0,0}, d1[8] = {0,0,0,0,0,0,0,0};
  for (int hh = 0; hh < ksplit; hh++) {
    uint4 u0 = *(const uint4*)(seg + (size_t)hh * SEGHALF_SHORTS + (size_t)sp.x * 512 + c0);
    uint4 u1 = *(const uint4*)(seg + (size_t)hh * SEGHALF_SHORTS + (size_t)sp.y * 512 + c0);
    const unsigned short* s0 = (const unsigned short*)&u0;
    const unsigned short* s1 = (const unsigned short*)&u1;
#pragma unroll
    for (int j = 0; j < 8; j++) { d0[j] += bf2f(s0[j]); d1[j] += bf2f(s1[j]); }
  }
  float b0[8], b1[8];
  *(float4*)&b0[0] = *(const float4*)(db + e.x * DWN + c0);
  *(float4*)&b0[4] = *(const float4*)(db + e.x * DWN + c0 + 4);
  *(float4*)&b1[0] = *(const float4*)(db + e.y * DWN + c0);
  *(float4*)&b1[4] = *(const float4*)(db + e.y * DWN + c0 + 4);

  unsigned short o[8];
#pragma unroll
  for (int j = 0; j < 8; j++) {
    float xx = p.x * (d0[j] + b0[j]) + p.y * (d1[j] + b1[j]);
    float inner = 0.7978845608028654f * (xx + 0.044715f * xx * xx * xx);
    o[j] = f2bf(0.5f * xx * (1.0f + tanhf(inner)));
  }
  *(uint4*)(h + (size_t)n * DWN + c0) = *(const uint4*)o;
}

// ---------------- up-proj: bf16 MFMA, 256x256, BK=64, K=512, 8 waves, counted-vmcnt ----------
// Same T3+T4+T5 pipeline as down: 8 loads/wave/tile, steady 16 outstanding, vmcnt(8) waits
// for the older tile only. Grid = 256 blocks = exactly 1/CU. FMA order unchanged -> out
// bit-identical. XCD swizzle: col-block fastest (uwb L2-resident).
__global__ __launch_bounds__(512, 2) void up_mfma_kernel(
    const unsigned short* __restrict__ h, const unsigned short* __restrict__ uwb,
    const float* __restrict__ ub, float* __restrict__ out)
{
  __shared__ unsigned short smem[65536];   // 2 x (A 16384 + B 16384) shorts = 128KB

  int wg  = blockIdx.x;                    // grid = 256
  int cpx = gridDim.x >> 3;                // 32
  int logical = (wg & 7) * cpx + (wg >> 3);
  int row0 = (logical >> 3) * 256;
  int col0 = (logical & 7) * 256;          // col fastest

  int tid = threadIdx.x;
  const int l = tid & 63, w = tid >> 6;    // 8 waves
  const int wm = w & 1, wn = w >> 1;       // 2M x 4N
  const int lm = l & 15, quad = l >> 4;

  const unsigned short* agp[4];
  const unsigned short* bgp[4];
#pragma unroll
  for (int i = 0; i < 4; i++) {            // A,B: 256 rows = 32 groups, 4/wave each
    int g = w * 4 + i;
    int rr = g * 8 + (l & 7);
    int kc = l >> 3;
    agp[i] = h   + (size_t)(row0 + rr) * DWN + kc * 8;
    bgp[i] = uwb + (size_t)(col0 + rr) * DWN + kc * 8;
  }

  int am_off[8], bn_off[4];
#pragma unroll
  for (int mi = 0; mi < 8; mi++) {
    int m = wm * 128 + mi * 16 + lm;
    am_off[mi] = (m >> 3) * 512 + (m & 7) * 8 + quad * 64;
  }
#pragma unroll
  for (int ni = 0; ni < 4; ni++) {
    int nn = wn * 64 + ni * 16 + lm;
    bn_off[ni] = (nn >> 3) * 512 + (nn & 7) * 8 + quad * 64;
  }

  f32x4 acc[8][4] = {};

#define USTAGE(BUF, T) do {                                                   \
    int k0_ = (T) * 64;                                                       \
    unsigned short* Ap_ = smem + (BUF) * 32768;                               \
    _Pragma("unroll") for (int i = 0; i < 4; i++) {                           \
      int g_ = w * 4 + i;                                                     \
      ASYNC16(agp[i] + k0_, &Ap_[g_ * 512]);                                  \
      ASYNC16(bgp[i] + k0_, &Ap_[16384 + g_ * 512]);                          \
    }                                                                         \
  } while (0)

  USTAGE(0, 0);
  USTAGE(1, 1);
  asm volatile("s_waitcnt vmcnt(8)" ::: "memory");
  __builtin_amdgcn_s_barrier();

  int cur = 0;
#define UTILE(STAGE_STMT, WAIT_STMT) do {                                     \
    unsigned short* As = smem + cur * 32768;                                  \
    unsigned short* Bs = As + 16384;                                          \
    bf16x8 a0[8], b0[4], a1[8], b1[4];                                        \
    _Pragma("unroll") for (int mi = 0; mi < 8; mi++) a0[mi] = *(const bf16x8*)&As[am_off[mi]]; \
    _Pragma("unroll") for (int ni = 0; ni < 4; ni++) b0[ni] = *(const bf16x8*)&Bs[bn_off[ni]]; \
    __builtin_amdgcn_s_setprio(1);                                            \
    _Pragma("unroll") for (int mi = 0; mi < 8; mi++)                          \
      _Pragma("unroll") for (int ni = 0; ni < 4; ni++)                        \
        acc[mi][ni] = __builtin_amdgcn_mfma_f32_16x16x32_bf16(a0[mi], b0[ni], acc[mi][ni], 0, 0, 0); \
    __builtin_amdgcn_s_setprio(0);                                            \
    _Pragma("unroll") for (int mi = 0; mi < 8; mi++) a1[mi] = *(const bf16x8*)&As[am_off[mi] + 256]; \
    _Pragma("unroll") for (int ni = 0; ni < 4; ni++) b1[ni] = *(const bf16x8*)&Bs[bn_off[ni] + 256]; \
    asm volatile("s_waitcnt lgkmcnt(0)" ::: "memory");                        \
    __builtin_amdgcn_sched_barrier(0);                                        \
    __builtin_amdgcn_s_barrier();                                             \
    STAGE_STMT;                                                               \
    __builtin_amdgcn_s_setprio(1);                                            \
    _Pragma("unroll") for (int mi = 0; mi < 8; mi++)                          \
      _Pragma("unroll") for (int ni = 0; ni < 4; ni++)                        \
        acc[mi][ni] = __builtin_amdgcn_mfma_f32_16x16x32_bf16(a1[mi], b1[ni], acc[mi][ni], 0, 0, 0); \
    __builtin_amdgcn_s_setprio(0);                                            \
    WAIT_STMT;                                                                \
  } while (0)

  const int nt = DWN / 64;   // 8
  for (int it = 0; it < nt - 2; ++it) {
    UTILE(USTAGE(cur, it + 2), VMWAIT_BAR(8));
    cur ^= 1;
  }
  UTILE(NOSTMT, VMWAIT_BAR(0));
  cur ^= 1;
  UTILE(NOSTMT, NOSTMT);
#undef UTILE
#undef USTAGE

  float ubv[4];
#pragma unroll
  for (int ni = 0; ni < 4; ni++)
    ubv[ni] = ub[col0 + wn * 64 + ni * 16 + lm];
#pragma unroll
  for (int mi = 0; mi < 8; mi++) {
#pragma unroll
    for (int reg = 0; reg < 4; reg++) {
      int m = row0 + wm * 128 + mi * 16 + quad * 4 + reg;
      float* orow = out + (size_t)m * HID;
#pragma unroll
      for (int ni = 0; ni < 4; ni++) {
        int gc = col0 + wn * 64 + ni * 16 + lm;
        orow[gc] = acc[mi][ni][reg] + ubv[ni];
      }
    }
  }
}

extern "C" void kernel_launch(void* const* d_in, const int* in_sizes, int n_in,
                              void* d_out, int out_size, void* d_ws, size_t ws_size,
                              hipStream_t stream)
{
  const float* x  = (const float*)d_in[0];
  const float* gw = (const float*)d_in[1];
  const float* dw = (const float*)d_in[2];
  const float* db = (const float*)d_in[3];
  const float* uw = (const float*)d_in[4];
  const float* ub = (const float*)d_in[5];
  float* out = (float*)d_out;

  char* ws = (char*)d_ws;
  unsigned short* xb   = (unsigned short*)(ws + OFF_XB);
  unsigned short* dwb  = (unsigned short*)(ws + OFF_DWB);
  unsigned short* uwb  = (unsigned short*)(ws + OFF_UWB);
  unsigned short* h    = (unsigned short*)(ws + OFF_H);
  unsigned short* seg  = (unsigned short*)(ws + OFF_SEG);
  int*    tok    = (int*)(ws + OFF_TOK);
  int2*   spos   = (int2*)(ws + OFF_SPOS);
  int2*   eidx   = (int2*)(ws + OFF_EIDX);
  float2* pvals  = (float2*)(ws + OFF_PVAL);
  int*    counts = (int*)(ws + OFF_COUNTS);
  int*    base   = (int*)(ws + OFF_BASE);
  int*    cursor = (int*)(ws + OFF_CURSOR);
  float*  colsum = (float*)(ws + OFF_COLSUM);

  // split-K only if the workspace is big enough (ws_size constant per session -> same work each call)
  const int ksplit = (ws_size >= (size_t)WS_NEED2) ? 2 : 1;
  const int kcount = (HID / 64) / ksplit;

  hipMemsetAsync(tok, 0xFF, PADSLOT * sizeof(int), stream);     // token = -1 padding
  hipMemsetAsync(counts, 0, 320, stream);                        // counts/base/cursor/colsum

  // x cast is fused into gate_kernel (reads x once, writes xb)
  cast8_kernel<<<(NEXP * DWN * HID) / 8 / 256, 256, 0, stream>>>(dw, dwb);
  cast8_kernel<<<(HID * DWN) / 8 / 256, 256, 0, stream>>>(uw, uwb);

  gate_kernel<<<NTOK / 8, 256, 0, stream>>>(x, gw, eidx, pvals, xb);
  hist_kernel<<<NTOK / 256, 256, 0, stream>>>(eidx, pvals, counts, colsum);
  scan_loss_kernel<<<1, 64, 0, stream>>>(counts, base, colsum, out + (size_t)NTOK * HID);
  scatter_kernel<<<NTOK / 256, 256, 0, stream>>>(eidx, base, cursor, tok, spos);

  down_mfma_kernel<<<DGRID_HALF * ksplit, 512, 0, stream>>>(xb, dwb, base, tok, seg, kcount);

  combine_gelu_kernel<<<NTOK / 4, 256, 0, stream>>>(seg, spos, pvals, eidx, db, h, ksplit);

  up_mfma_kernel<<<(NTOK / 256) * (HID / 256), 512, 0, stream>>>(h, uwb, ub, out);
}

// Round 7
// 373.448 us; speedup vs baseline: 1.2211x; 1.0021x over previous
//
#include <hip/hip_runtime.h>
#include <hip/hip_bf16.h>
#include <math.h>

// Problem constants
#define NTOK   8192      // B*S
#define HID    2048
#define DWN    512
#define NEXP   16
#define PADSLOT 18432    // 144*128 >= 16384 + 16*127 (segments 128-aligned)
#define NSLOTBLK 144     // PADSLOT/128
#define DGRID_HALF (NSLOTBLK * (DWN / 128))   // 576 blocks per K-half (slot-blocks x out-blocks, BN=128)

// ws layout (bytes). H overlays DWB (dwb dead after down_mfma; combine writes h after).
#define OFF_XB       0                       // bf16[NTOK*HID]       = 33554432
#define OFF_DWB      33554432                // bf16[NEXP*DWN*HID]   = 33554432
#define OFF_H        33554432                // bf16[NTOK*DWN]       = 8388608 (overlay on DWB)
#define OFF_UWB      67108864                // bf16[HID*DWN]        = 2097152
#define OFF_TOK      69206016                // int[PADSLOT]         = 73728
#define OFF_SPOS     69279744                // int2[NTOK]           = 65536
#define OFF_EIDX     69345280                // int2[NTOK]           = 65536
#define OFF_PVAL     69410816                // float2[NTOK]         = 65536
#define OFF_COUNTS   69476352                // int[16]
#define OFF_BASE     69476416                // int[17] (padded to 128)
#define OFF_CURSOR   69476544                // int[16]
#define OFF_COLSUM   69476608                // float[16]
#define OFF_SEG      69476672                // bf16[ksplit][PADSLOT*512]
#define SEGHALF_SHORTS 9437184               // PADSLOT*512
#define SEGHALF_BYTES  18874368
#define WS_NEED1     (OFF_SEG + 1 * SEGHALF_BYTES)   //  88.4 MB
#define WS_NEED2     (OFF_SEG + 2 * SEGHALF_BYTES)   // 107.2 MB

typedef __attribute__((ext_vector_type(8))) __bf16 bf16x8;
typedef __attribute__((ext_vector_type(4))) float f32x4;

// async 16B/lane global->LDS copy (LDS dest is wave-uniform base; HW adds lane*16)
#define ASYNC16(gsrc, ldst) \
  __builtin_amdgcn_global_load_lds((const __attribute__((address_space(1))) unsigned int*)(gsrc), \
                                   (__attribute__((address_space(3))) unsigned int*)(ldst), 16, 0, 0)

// counted-vmcnt wait + barrier (T4): N = loads still allowed in flight
#define VMWAIT_BAR(N) do { asm volatile("s_waitcnt vmcnt(" #N ")" ::: "memory"); \
                           __builtin_amdgcn_s_barrier(); } while (0)
#define NOSTMT ((void)0)

__device__ inline unsigned short f2bf(float f) {
  unsigned int u = __float_as_uint(f);
  unsigned int r = (u + 0x7FFFu + ((u >> 16) & 1u)) >> 16;
  return (unsigned short)r;
}
__device__ inline float bf2f(unsigned short s) {
  return __uint_as_float((unsigned int)s << 16);
}

// ---------------- fp32 -> bf16 cast, 8 elems/thread ----------------
__global__ __launch_bounds__(256) void cast8_kernel(const float* __restrict__ src,
                                                    unsigned short* __restrict__ dst)
{
  size_t i = ((size_t)blockIdx.x * 256 + threadIdx.x) * 8;
  float4 a = *(const float4*)(src + i);
  float4 b = *(const float4*)(src + i + 4);
  unsigned short o[8];
  o[0]=f2bf(a.x); o[1]=f2bf(a.y); o[2]=f2bf(a.z); o[3]=f2bf(a.w);
  o[4]=f2bf(b.x); o[5]=f2bf(b.y); o[6]=f2bf(b.z); o[7]=f2bf(b.w);
  *(uint4*)(dst + i) = *(const uint4*)o;
}

// ---------------- gating: LDS-staged gate weights, 2 tokens/wave, f64 accumulation ----------
// (passed R4/R5/R6; unchanged) gw staged per-block in 16KB chunks via global_load_lds (zero
// VGPR), double-buffered; FMA chain reads LDS instead of L2. Numerics bit-identical to R2.
__global__ __launch_bounds__(256, 4) void gate_kernel(
    const float* __restrict__ x, const float* __restrict__ gw,
    int2* __restrict__ eidx, float2* __restrict__ pvals,
    unsigned short* __restrict__ xbw)
{
  __shared__ float gws[2][NEXP * 256];   // 2 x 16KB double-buffered gw chunk

  int lane = threadIdx.x & 63;
  int wave = threadIdx.x >> 6;
  int n0 = (blockIdx.x * 4 + wave) * 2;          // 2 tokens per wave
  const float* xr0 = x + (size_t)n0 * HID;
  const float* xr1 = xr0 + HID;
  unsigned short* xw0 = xbw + (size_t)n0 * HID;
  unsigned short* xw1 = xw0 + HID;

  double acc0[NEXP], acc1[NEXP];
#pragma unroll
  for (int e = 0; e < NEXP; e++) { acc0[e] = 0.0; acc1[e] = 0.0; }

  // prologue: stage chunk 0 (each wave stages 4 expert rows of 256 floats = 1KB each)
#pragma unroll
  for (int r = 0; r < 4; r++) {
    int e = r * 4 + wave;
    ASYNC16(gw + (size_t)e * HID + lane * 4, &gws[0][e * 256]);
  }
  __syncthreads();                                // vmcnt(0): chunk 0 ready

  int cur = 0;
  for (int c = 0; c < HID / 256; c++) {
    int d0 = c * 256;
    // prefetch next gw chunk into the other buffer (zero-VGPR async)
    if (c + 1 < HID / 256) {
#pragma unroll
      for (int r = 0; r < 4; r++) {
        int e = r * 4 + wave;
        ASYNC16(gw + (size_t)e * HID + d0 + 256 + lane * 4, &gws[cur ^ 1][e * 256]);
      }
    }
    int d = d0 + lane * 4;
    float4 xv0 = *(const float4*)(xr0 + d);
    float4 xv1 = *(const float4*)(xr1 + d);
    unsigned short o0[4] = {f2bf(xv0.x), f2bf(xv0.y), f2bf(xv0.z), f2bf(xv0.w)};
    unsigned short o1[4] = {f2bf(xv1.x), f2bf(xv1.y), f2bf(xv1.z), f2bf(xv1.w)};
    *(uint2*)(xw0 + d) = *(const uint2*)o0;
    *(uint2*)(xw1 + d) = *(const uint2*)o1;
    double x00 = (double)xv0.x, x01 = (double)xv0.y, x02 = (double)xv0.z, x03 = (double)xv0.w;
    double x10 = (double)xv1.x, x11 = (double)xv1.y, x12 = (double)xv1.z, x13 = (double)xv1.w;
    const float* gs = &gws[cur][lane * 4];
#pragma unroll
    for (int e = 0; e < NEXP; e++) {
      float4 g = *(const float4*)(gs + e * 256);
      double g0 = (double)g.x, g1 = (double)g.y, g2 = (double)g.z, g3 = (double)g.w;
      double s0 = acc0[e], s1 = acc1[e];
      s0 = fma(x00, g0, s0); s0 = fma(x01, g1, s0);
      s0 = fma(x02, g2, s0); s0 = fma(x03, g3, s0);
      s1 = fma(x10, g0, s1); s1 = fma(x11, g1, s1);
      s1 = fma(x12, g2, s1); s1 = fma(x13, g3, s1);
      acc0[e] = s0; acc1[e] = s1;
    }
    __syncthreads();                              // chunk consumed; next chunk's loads drained
    cur ^= 1;
  }

  // butterfly reduce across 64 lanes (all lanes end with the totals)
#define RED(v) { v += __shfl_xor(v,32,64); v += __shfl_xor(v,16,64); v += __shfl_xor(v,8,64); \
                 v += __shfl_xor(v,4,64);  v += __shfl_xor(v,2,64);  v += __shfl_xor(v,1,64); }
#pragma unroll
  for (int e = 0; e < NEXP; e++) { RED(acc0[e]) RED(acc1[e]) }
#undef RED

#define TOPSEL(ACC, N) { \
    double v0 = -1e300, v1 = -1e300; int i0 = 0, i1 = 0; \
    _Pragma("unroll") \
    for (int e = 0; e < NEXP; e++) { \
      double v = ACC[e]; \
      if (v > v0) { v1 = v0; i1 = i0; v0 = v; i0 = e; } \
      else if (v > v1) { v1 = v; i1 = e; } \
    } \
    double ex = exp(v1 - v0); \
    double denom = 1.0 + ex; \
    eidx[N]  = make_int2(i0, i1); \
    pvals[N] = make_float2((float)(1.0 / denom), (float)(ex / denom)); \
  }
  if (lane == 0) TOPSEL(acc0, n0)
  if (lane == 1) TOPSEL(acc1, n0 + 1)
#undef TOPSEL
}

// ---------------- histogram: counts + colsum via LDS bins ----------------
__global__ __launch_bounds__(256) void hist_kernel(
    const int2* __restrict__ eidx, const float2* __restrict__ pvals,
    int* __restrict__ counts, float* __restrict__ colsum)
{
  __shared__ int   cbin[NEXP];
  __shared__ float lbin[NEXP];
  if (threadIdx.x < NEXP) { cbin[threadIdx.x] = 0; lbin[threadIdx.x] = 0.f; }
  __syncthreads();
  int n = blockIdx.x * 256 + threadIdx.x;
  int2 e = eidx[n];
  float2 p = pvals[n];
  atomicAdd(&cbin[e.x], 1);  atomicAdd(&lbin[e.x], p.x);
  atomicAdd(&cbin[e.y], 1);  atomicAdd(&lbin[e.y], p.y);
  __syncthreads();
  if (threadIdx.x < NEXP) {
    atomicAdd(&counts[threadIdx.x], cbin[threadIdx.x]);
    atomicAdd(&colsum[threadIdx.x], lbin[threadIdx.x]);
  }
}

// ---------------- scan bases (128-aligned segments) + loss ----------------
__global__ void scan_loss_kernel(const int* __restrict__ counts, int* __restrict__ base,
                                 const float* __restrict__ colsum, float* __restrict__ loss_out)
{
  if (threadIdx.x == 0 && blockIdx.x == 0) {
    int acc = 0;
    for (int e = 0; e < NEXP; e++) { base[e] = acc; acc += (counts[e] + 127) & ~127; }
    base[NEXP] = acc;
    double s = 0.0;
    for (int e = 0; e < NEXP; e++) { double c = (double)colsum[e]; s += c * c; }
    loss_out[0] = (float)(1.6 * s / ((double)NTOK * (double)NTOK));
  }
}

// ---------------- scatter: wave-aggregated cursor atomics; records slot positions ----------------
__global__ __launch_bounds__(256) void scatter_kernel(
    const int2* __restrict__ eidx, const int* __restrict__ base, int* __restrict__ cursor,
    int* __restrict__ tok, int2* __restrict__ spos)
{
  int n = blockIdx.x * 256 + threadIdx.x;
  int lane = threadIdx.x & 63;
  int2 e = eidx[n];
  int myE[2] = {e.x, e.y};
  int myPos[2];
#pragma unroll
  for (int s = 0; s < 2; s++) {
    int eq = myE[s];
#pragma unroll
    for (int q = 0; q < NEXP; q++) {
      unsigned long long m = __ballot(eq == q);
      if (eq == q) {
        int cnt = __popcll(m);
        int pre = __popcll(m & ((1ull << lane) - 1ull));
        int b = 0;
        if (pre == 0) b = atomicAdd(&cursor[q], cnt);
        int leader = __ffsll((long long)m) - 1;
        b = __shfl(b, leader, 64);
        int pos = base[q] + b + pre;
        tok[pos] = n;
        myPos[s] = pos;
      }
    }
  }
  spos[n] = make_int2(myPos[0], myPos[1]);
}

// ---------------- grouped expert down-proj: bf16 MFMA, 128x128, BK=64, 4 waves ----------------
// R6 pipeline (T3+T4+T5, verified bit-exact) kept; tile shrunk back to 128x128 / 4 waves /
// 64KB LDS -> 2 RESIDENT blocks/CU. Rationale (R6 post-mortem): 96KB tile = 1 block/CU gave
// a 3-round tail (~30% loss) and zero cross-block overlap; 2-resident restores R4's overlap
// ON TOP of the counted-vmcnt pipeline. Grid 1152 (144 slot x 4 out x ksplit), 4.1 blocks/CU.
// 8 loads/wave/tile; steady 16 outstanding; vmcnt(8) waits only for the older tile.
// FMA order per acc element unchanged (kk0 then kk1) -> seg bit-identical.
__global__ __launch_bounds__(256, 2) void down_mfma_kernel(
    const unsigned short* __restrict__ xb, const unsigned short* __restrict__ dwb,
    const int* __restrict__ base, const int* __restrict__ tok,
    unsigned short* __restrict__ seg, int kcount)
{
  __shared__ unsigned short smem[32768];   // 2 x (A 8192 + B 8192) shorts = 64KB; epi 128x136

  int wg  = blockIdx.x;
  int cpx = gridDim.x >> 3;                 // blocks per XCD chunk (1152/8=144 or 576/8=72)
  int logical = (wg & 7) * cpx + (wg >> 3); // bijective XCD chunking
  int kh      = logical / DGRID_HALF;
  int r       = logical % DGRID_HALF;
  int slot0   = (r >> 2) * 128;             // slot-group
  int out0    = (r & 3) * 128;              // out-block fastest (A-tile reuse)

  if (slot0 >= base[NEXP]) return;          // uniform per block
  int e = 0;
#pragma unroll
  for (int q = 1; q < NEXP; q++) if (base[q] <= slot0) e = q;
  int kbase = kh * kcount * 64;

  int tid = threadIdx.x;
  const int l = tid & 63, w = tid >> 6;     // 4 waves
  const int wm = w & 1, wn = w >> 1;        // 2M x 2N
  const int lm = l & 15, quad = l >> 4;

  const unsigned short* agp[4];
  const unsigned short* bgp[4];
#pragma unroll
  for (int i = 0; i < 4; i++) {             // A,B: 128 rows = 16 groups, 4/wave each
    int g = w * 4 + i;
    int rr = g * 8 + (l & 7);
    int kc = l >> 3;
    int t = tok[slot0 + rr];
    agp[i] = xb + (size_t)(t < 0 ? 0 : t) * HID + kbase + kc * 8;
    bgp[i] = dwb + ((size_t)e * DWN + out0 + rr) * HID + kbase + kc * 8;
  }

  int am_off[4], bn_off[4];
#pragma unroll
  for (int mi = 0; mi < 4; mi++) {
    int m = wm * 64 + mi * 16 + lm;
    am_off[mi] = (m >> 3) * 512 + (m & 7) * 8 + quad * 64;
    int nn = wn * 64 + mi * 16 + lm;
    bn_off[mi] = (nn >> 3) * 512 + (nn & 7) * 8 + quad * 64;
  }

  f32x4 acc[4][4] = {};

  // stage tile T into buffer BUF (8 loads/wave)
#define DSTAGE(BUF, T) do {                                                   \
    int k0_ = (T) * 64;                                                       \
    unsigned short* Ap_ = smem + (BUF) * 16384;                               \
    _Pragma("unroll") for (int i = 0; i < 4; i++) {                           \
      int g_ = w * 4 + i;                                                     \
      ASYNC16(agp[i] + k0_, &Ap_[g_ * 512]);                                  \
      ASYNC16(bgp[i] + k0_, &Ap_[8192 + g_ * 512]);                           \
    }                                                                         \
  } while (0)

  // prologue: tiles 0 and 1 in flight; wait for tile 0 only (8 newest still outstanding)
  DSTAGE(0, 0);
  DSTAGE(1, 1);
  asm volatile("s_waitcnt vmcnt(8)" ::: "memory");
  __builtin_amdgcn_s_barrier();

  int cur = 0;
#define DTILE(STAGE_STMT, WAIT_STMT) do {                                     \
    unsigned short* As = smem + cur * 16384;                                  \
    unsigned short* Bs = As + 8192;                                           \
    bf16x8 a0[4], b0[4], a1[4], b1[4];                                        \
    _Pragma("unroll") for (int mi = 0; mi < 4; mi++) {                        \
      a0[mi] = *(const bf16x8*)&As[am_off[mi]];                               \
      b0[mi] = *(const bf16x8*)&Bs[bn_off[mi]];                               \
    }                                                                         \
    __builtin_amdgcn_s_setprio(1);                                            \
    _Pragma("unroll") for (int mi = 0; mi < 4; mi++)                          \
      _Pragma("unroll") for (int ni = 0; ni < 4; ni++)                        \
        acc[mi][ni] = __builtin_amdgcn_mfma_f32_16x16x32_bf16(a0[mi], b0[ni], acc[mi][ni], 0, 0, 0); \
    __builtin_amdgcn_s_setprio(0);                                            \
    _Pragma("unroll") for (int mi = 0; mi < 4; mi++) {                        \
      a1[mi] = *(const bf16x8*)&As[am_off[mi] + 256];                         \
      b1[mi] = *(const bf16x8*)&Bs[bn_off[mi] + 256];                         \
    }                                                                         \
    asm volatile("s_waitcnt lgkmcnt(0)" ::: "memory");                        \
    __builtin_amdgcn_sched_barrier(0);                                        \
    __builtin_amdgcn_s_barrier();          /* all waves done reading buf[cur] */ \
    STAGE_STMT;                                                               \
    __builtin_amdgcn_s_setprio(1);                                            \
    _Pragma("unroll") for (int mi = 0; mi < 4; mi++)                          \
      _Pragma("unroll") for (int ni = 0; ni < 4; ni++)                        \
        acc[mi][ni] = __builtin_amdgcn_mfma_f32_16x16x32_bf16(a1[mi], b1[ni], acc[mi][ni], 0, 0, 0); \
    __builtin_amdgcn_s_setprio(0);                                            \
    WAIT_STMT;                                                                \
  } while (0)

  for (int it = 0; it < kcount - 2; ++it) {
    DTILE(DSTAGE(cur, it + 2), VMWAIT_BAR(8));
    cur ^= 1;
  }
  DTILE(NOSTMT, VMWAIT_BAR(0));   // tile kcount-2: drain last tile's loads
  cur ^= 1;
  DTILE(NOSTMT, NOSTMT);          // tile kcount-1
#undef DTILE
#undef DSTAGE

  // epilogue: stage bf16 tile in LDS (stride 136 shorts = 272B, 16B-aligned, bank-spread),
  // then fully-coalesced 16B global stores. No atomics.
  __syncthreads();
#pragma unroll
  for (int mi = 0; mi < 4; mi++)
#pragma unroll
    for (int reg = 0; reg < 4; reg++) {
      int m = wm * 64 + mi * 16 + quad * 4 + reg;
#pragma unroll
      for (int ni = 0; ni < 4; ni++) {
        int c = wn * 64 + ni * 16 + lm;
        smem[m * 136 + c] = f2bf(acc[mi][ni][reg]);
      }
    }
  __syncthreads();
#pragma unroll
  for (int it2 = 0; it2 < 8; it2++) {
    int chunk = it2 * 256 + tid;
    int row = chunk >> 4, off = (chunk & 15) * 8;
    uint4 v = *(const uint4*)&smem[row * 136 + off];
    *(uint4*)&seg[(size_t)kh * SEGHALF_SHORTS + (size_t)(slot0 + row) * 512 + out0 + off] = v;
  }
}

// ---------------- combine (gather 2 slots x ksplit halves) + bias + gelu_new -> h bf16 ----------------
__global__ __launch_bounds__(256) void combine_gelu_kernel(
    const unsigned short* __restrict__ seg, const int2* __restrict__ spos,
    const float2* __restrict__ pv, const int2* __restrict__ eix,
    const float* __restrict__ db, unsigned short* __restrict__ h, int ksplit)
{
  int n = blockIdx.x * 4 + (threadIdx.x >> 6);
  int lane = threadIdx.x & 63;
  int c0 = lane * 8;
  int2 sp = spos[n];
  float2 p = pv[n];
  int2 e = eix[n];

  float d0[8] = {0,0,0,0,0,0,0,0}, d1[8] = {0,0,0,0,0,0,0,0};
  for (int hh = 0; hh < ksplit; hh++) {
    uint4 u0 = *(const uint4*)(seg + (size_t)hh * SEGHALF_SHORTS + (size_t)sp.x * 512 + c0);
    uint4 u1 = *(const uint4*)(seg + (size_t)hh * SEGHALF_SHORTS + (size_t)sp.y * 512 + c0);
    const unsigned short* s0 = (const unsigned short*)&u0;
    const unsigned short* s1 = (const unsigned short*)&u1;
#pragma unroll
    for (int j = 0; j < 8; j++) { d0[j] += bf2f(s0[j]); d1[j] += bf2f(s1[j]); }
  }
  float b0[8], b1[8];
  *(float4*)&b0[0] = *(const float4*)(db + e.x * DWN + c0);
  *(float4*)&b0[4] = *(const float4*)(db + e.x * DWN + c0 + 4);
  *(float4*)&b1[0] = *(const float4*)(db + e.y * DWN + c0);
  *(float4*)&b1[4] = *(const float4*)(db + e.y * DWN + c0 + 4);

  unsigned short o[8];
#pragma unroll
  for (int j = 0; j < 8; j++) {
    float xx = p.x * (d0[j] + b0[j]) + p.y * (d1[j] + b1[j]);
    float inner = 0.7978845608028654f * (xx + 0.044715f * xx * xx * xx);
    o[j] = f2bf(0.5f * xx * (1.0f + tanhf(inner)));
  }
  *(uint4*)(h + (size_t)n * DWN + c0) = *(const uint4*)o;
}

// ---------------- up-proj: bf16 MFMA, 256x256, BK=64, K=512, 8 waves, counted-vmcnt ----------
// (passed R6; unchanged) 8 loads/wave/tile, steady 16 outstanding, vmcnt(8) waits for the
// older tile only. Grid = 256 blocks = exactly 1/CU (no tail). XCD swizzle col-fastest.
__global__ __launch_bounds__(512, 2) void up_mfma_kernel(
    const unsigned short* __restrict__ h, const unsigned short* __restrict__ uwb,
    const float* __restrict__ ub, float* __restrict__ out)
{
  __shared__ unsigned short smem[65536];   // 2 x (A 16384 + B 16384) shorts = 128KB

  int wg  = blockIdx.x;                    // grid = 256
  int cpx = gridDim.x >> 3;                // 32
  int logical = (wg & 7) * cpx + (wg >> 3);
  int row0 = (logical >> 3) * 256;
  int col0 = (logical & 7) * 256;          // col fastest

  int tid = threadIdx.x;
  const int l = tid & 63, w = tid >> 6;    // 8 waves
  const int wm = w & 1, wn = w >> 1;       // 2M x 4N
  const int lm = l & 15, quad = l >> 4;

  const unsigned short* agp[4];
  const unsigned short* bgp[4];
#pragma unroll
  for (int i = 0; i < 4; i++) {            // A,B: 256 rows = 32 groups, 4/wave each
    int g = w * 4 + i;
    int rr = g * 8 + (l & 7);
    int kc = l >> 3;
    agp[i] = h   + (size_t)(row0 + rr) * DWN + kc * 8;
    bgp[i] = uwb + (size_t)(col0 + rr) * DWN + kc * 8;
  }

  int am_off[8], bn_off[4];
#pragma unroll
  for (int mi = 0; mi < 8; mi++) {
    int m = wm * 128 + mi * 16 + lm;
    am_off[mi] = (m >> 3) * 512 + (m & 7) * 8 + quad * 64;
  }
#pragma unroll
  for (int ni = 0; ni < 4; ni++) {
    int nn = wn * 64 + ni * 16 + lm;
    bn_off[ni] = (nn >> 3) * 512 + (nn & 7) * 8 + quad * 64;
  }

  f32x4 acc[8][4] = {};

#define USTAGE(BUF, T) do {                                                   \
    int k0_ = (T) * 64;                                                       \
    unsigned short* Ap_ = smem + (BUF) * 32768;                               \
    _Pragma("unroll") for (int i = 0; i < 4; i++) {                           \
      int g_ = w * 4 + i;                                                     \
      ASYNC16(agp[i] + k0_, &Ap_[g_ * 512]);                                  \
      ASYNC16(bgp[i] + k0_, &Ap_[16384 + g_ * 512]);                          \
    }                                                                         \
  } while (0)

  USTAGE(0, 0);
  USTAGE(1, 1);
  asm volatile("s_waitcnt vmcnt(8)" ::: "memory");
  __builtin_amdgcn_s_barrier();

  int cur = 0;
#define UTILE(STAGE_STMT, WAIT_STMT) do {                                     \
    unsigned short* As = smem + cur * 32768;                                  \
    unsigned short* Bs = As + 16384;                                          \
    bf16x8 a0[8], b0[4], a1[8], b1[4];                                        \
    _Pragma("unroll") for (int mi = 0; mi < 8; mi++) a0[mi] = *(const bf16x8*)&As[am_off[mi]]; \
    _Pragma("unroll") for (int ni = 0; ni < 4; ni++) b0[ni] = *(const bf16x8*)&Bs[bn_off[ni]]; \
    __builtin_amdgcn_s_setprio(1);                                            \
    _Pragma("unroll") for (int mi = 0; mi < 8; mi++)                          \
      _Pragma("unroll") for (int ni = 0; ni < 4; ni++)                        \
        acc[mi][ni] = __builtin_amdgcn_mfma_f32_16x16x32_bf16(a0[mi], b0[ni], acc[mi][ni], 0, 0, 0); \
    __builtin_amdgcn_s_setprio(0);                                            \
    _Pragma("unroll") for (int mi = 0; mi < 8; mi++) a1[mi] = *(const bf16x8*)&As[am_off[mi] + 256]; \
    _Pragma("unroll") for (int ni = 0; ni < 4; ni++) b1[ni] = *(const bf16x8*)&Bs[bn_off[ni] + 256]; \
    asm volatile("s_waitcnt lgkmcnt(0)" ::: "memory");                        \
    __builtin_amdgcn_sched_barrier(0);                                        \
    __builtin_amdgcn_s_barrier();                                             \
    STAGE_STMT;                                                               \
    __builtin_amdgcn_s_setprio(1);                                            \
    _Pragma("unroll") for (int mi = 0; mi < 8; mi++)                          \
      _Pragma("unroll") for (int ni = 0; ni < 4; ni++)                        \
        acc[mi][ni] = __builtin_amdgcn_mfma_f32_16x16x32_bf16(a1[mi], b1[ni], acc[mi][ni], 0, 0, 0); \
    __builtin_amdgcn_s_setprio(0);                                            \
    WAIT_STMT;                                                                \
  } while (0)

  const int nt = DWN / 64;   // 8
  for (int it = 0; it < nt - 2; ++it) {
    UTILE(USTAGE(cur, it + 2), VMWAIT_BAR(8));
    cur ^= 1;
  }
  UTILE(NOSTMT, VMWAIT_BAR(0));
  cur ^= 1;
  UTILE(NOSTMT, NOSTMT);
#undef UTILE
#undef USTAGE

  float ubv[4];
#pragma unroll
  for (int ni = 0; ni < 4; ni++)
    ubv[ni] = ub[col0 + wn * 64 + ni * 16 + lm];
#pragma unroll
  for (int mi = 0; mi < 8; mi++) {
#pragma unroll
    for (int reg = 0; reg < 4; reg++) {
      int m = row0 + wm * 128 + mi * 16 + quad * 4 + reg;
      float* orow = out + (size_t)m * HID;
#pragma unroll
      for (int ni = 0; ni < 4; ni++) {
        int gc = col0 + wn * 64 + ni * 16 + lm;
        orow[gc] = acc[mi][ni][reg] + ubv[ni];
      }
    }
  }
}

extern "C" void kernel_launch(void* const* d_in, const int* in_sizes, int n_in,
                              void* d_out, int out_size, void* d_ws, size_t ws_size,
                              hipStream_t stream)
{
  const float* x  = (const float*)d_in[0];
  const float* gw = (const float*)d_in[1];
  const float* dw = (const float*)d_in[2];
  const float* db = (const float*)d_in[3];
  const float* uw = (const float*)d_in[4];
  const float* ub = (const float*)d_in[5];
  float* out = (float*)d_out;

  char* ws = (char*)d_ws;
  unsigned short* xb   = (unsigned short*)(ws + OFF_XB);
  unsigned short* dwb  = (unsigned short*)(ws + OFF_DWB);
  unsigned short* uwb  = (unsigned short*)(ws + OFF_UWB);
  unsigned short* h    = (unsigned short*)(ws + OFF_H);
  unsigned short* seg  = (unsigned short*)(ws + OFF_SEG);
  int*    tok    = (int*)(ws + OFF_TOK);
  int2*   spos   = (int2*)(ws + OFF_SPOS);
  int2*   eidx   = (int2*)(ws + OFF_EIDX);
  float2* pvals  = (float2*)(ws + OFF_PVAL);
  int*    counts = (int*)(ws + OFF_COUNTS);
  int*    base   = (int*)(ws + OFF_BASE);
  int*    cursor = (int*)(ws + OFF_CURSOR);
  float*  colsum = (float*)(ws + OFF_COLSUM);

  // split-K only if the workspace is big enough (ws_size constant per session -> same work each call)
  const int ksplit = (ws_size >= (size_t)WS_NEED2) ? 2 : 1;
  const int kcount = (HID / 64) / ksplit;

  hipMemsetAsync(tok, 0xFF, PADSLOT * sizeof(int), stream);     // token = -1 padding
  hipMemsetAsync(counts, 0, 320, stream);                        // counts/base/cursor/colsum

  // x cast is fused into gate_kernel (reads x once, writes xb)
  cast8_kernel<<<(NEXP * DWN * HID) / 8 / 256, 256, 0, stream>>>(dw, dwb);
  cast8_kernel<<<(HID * DWN) / 8 / 256, 256, 0, stream>>>(uw, uwb);

  gate_kernel<<<NTOK / 8, 256, 0, stream>>>(x, gw, eidx, pvals, xb);
  hist_kernel<<<NTOK / 256, 256, 0, stream>>>(eidx, pvals, counts, colsum);
  scan_loss_kernel<<<1, 64, 0, stream>>>(counts, base, colsum, out + (size_t)NTOK * HID);
  scatter_kernel<<<NTOK / 256, 256, 0, stream>>>(eidx, base, cursor, tok, spos);

  down_mfma_kernel<<<DGRID_HALF * ksplit, 256, 0, stream>>>(xb, dwb, base, tok, seg, kcount);

  combine_gelu_kernel<<<NTOK / 4, 256, 0, stream>>>(seg, spos, pvals, eidx, db, h, ksplit);

  up_mfma_kernel<<<(NTOK / 256) * (HID / 256), 512, 0, stream>>>(h, uwb, ub, out);
}

// Round 8
// 372.556 us; speedup vs baseline: 1.2240x; 1.0024x over previous
//
#include <hip/hip_runtime.h>
#include <hip/hip_bf16.h>
#include <math.h>

// Problem constants
#define NTOK   8192      // B*S
#define HID    2048
#define DWN    512
#define NEXP   16
#define PADSLOT 18432    // 144*128 >= 16384 + 16*127 (segments 128-aligned)
#define NSLOTBLK 144     // PADSLOT/128
#define DGRID_HALF (NSLOTBLK * (DWN / 128))   // 576 blocks per K-half (slot-blocks x out-blocks, BN=128)

// ws layout (bytes). H overlays DWB (dwb dead after down_mfma; combine writes h after).
#define OFF_XB       0                       // bf16[NTOK*HID]       = 33554432
#define OFF_DWB      33554432                // bf16[NEXP*DWN*HID]   = 33554432
#define OFF_H        33554432                // bf16[NTOK*DWN]       = 8388608 (overlay on DWB)
#define OFF_UWB      67108864                // bf16[HID*DWN]        = 2097152
#define OFF_TOK      69206016                // int[PADSLOT]         = 73728
#define OFF_SPOS     69279744                // int2[NTOK]           = 65536
#define OFF_EIDX     69345280                // int2[NTOK]           = 65536
#define OFF_PVAL     69410816                // float2[NTOK]         = 65536
#define OFF_COUNTS   69476352                // int[16]
#define OFF_BASE     69476416                // int[17] (padded to 128)
#define OFF_CURSOR   69476544                // int[16]
#define OFF_COLSUM   69476608                // float[16]
#define OFF_SEG      69476672                // bf16[ksplit][PADSLOT*512]
#define SEGHALF_SHORTS 9437184               // PADSLOT*512
#define SEGHALF_BYTES  18874368
#define WS_NEED1     (OFF_SEG + 1 * SEGHALF_BYTES)   //  88.4 MB
#define WS_NEED2     (OFF_SEG + 2 * SEGHALF_BYTES)   // 107.2 MB

typedef __attribute__((ext_vector_type(8))) __bf16 bf16x8;
typedef __attribute__((ext_vector_type(4))) float f32x4;

// async 16B/lane global->LDS copy (LDS dest is wave-uniform base; HW adds lane*16)
#define ASYNC16(gsrc, ldst) \
  __builtin_amdgcn_global_load_lds((const __attribute__((address_space(1))) unsigned int*)(gsrc), \
                                   (__attribute__((address_space(3))) unsigned int*)(ldst), 16, 0, 0)

// counted-vmcnt wait + barrier (T4): N = loads still allowed in flight
#define VMWAIT_BAR(N) do { asm volatile("s_waitcnt vmcnt(" #N ")" ::: "memory"); \
                           __builtin_amdgcn_s_barrier(); } while (0)
#define NOSTMT ((void)0)

__device__ inline unsigned short f2bf(float f) {
  unsigned int u = __float_as_uint(f);
  unsigned int r = (u + 0x7FFFu + ((u >> 16) & 1u)) >> 16;
  return (unsigned short)r;
}
__device__ inline float bf2f(unsigned short s) {
  return __uint_as_float((unsigned int)s << 16);
}

// ---------------- fp32 -> bf16 cast, 8 elems/thread ----------------
__global__ __launch_bounds__(256) void cast8_kernel(const float* __restrict__ src,
                                                    unsigned short* __restrict__ dst)
{
  size_t i = ((size_t)blockIdx.x * 256 + threadIdx.x) * 8;
  float4 a = *(const float4*)(src + i);
  float4 b = *(const float4*)(src + i + 4);
  unsigned short o[8];
  o[0]=f2bf(a.x); o[1]=f2bf(a.y); o[2]=f2bf(a.z); o[3]=f2bf(a.w);
  o[4]=f2bf(b.x); o[5]=f2bf(b.y); o[6]=f2bf(b.z); o[7]=f2bf(b.w);
  *(uint4*)(dst + i) = *(const uint4*)o;
}

// ---------------- gating: LDS-staged gate weights, 2 tokens/wave, f64 accumulation ----------
// (passed R4-R7; unchanged) gw staged per-block in 16KB chunks via global_load_lds (zero
// VGPR), double-buffered; FMA chain reads LDS instead of L2. Numerics bit-identical to R2.
__global__ __launch_bounds__(256, 4) void gate_kernel(
    const float* __restrict__ x, const float* __restrict__ gw,
    int2* __restrict__ eidx, float2* __restrict__ pvals,
    unsigned short* __restrict__ xbw)
{
  __shared__ float gws[2][NEXP * 256];   // 2 x 16KB double-buffered gw chunk

  int lane = threadIdx.x & 63;
  int wave = threadIdx.x >> 6;
  int n0 = (blockIdx.x * 4 + wave) * 2;          // 2 tokens per wave
  const float* xr0 = x + (size_t)n0 * HID;
  const float* xr1 = xr0 + HID;
  unsigned short* xw0 = xbw + (size_t)n0 * HID;
  unsigned short* xw1 = xw0 + HID;

  double acc0[NEXP], acc1[NEXP];
#pragma unroll
  for (int e = 0; e < NEXP; e++) { acc0[e] = 0.0; acc1[e] = 0.0; }

  // prologue: stage chunk 0 (each wave stages 4 expert rows of 256 floats = 1KB each)
#pragma unroll
  for (int r = 0; r < 4; r++) {
    int e = r * 4 + wave;
    ASYNC16(gw + (size_t)e * HID + lane * 4, &gws[0][e * 256]);
  }
  __syncthreads();                                // vmcnt(0): chunk 0 ready

  int cur = 0;
  for (int c = 0; c < HID / 256; c++) {
    int d0 = c * 256;
    // prefetch next gw chunk into the other buffer (zero-VGPR async)
    if (c + 1 < HID / 256) {
#pragma unroll
      for (int r = 0; r < 4; r++) {
        int e = r * 4 + wave;
        ASYNC16(gw + (size_t)e * HID + d0 + 256 + lane * 4, &gws[cur ^ 1][e * 256]);
      }
    }
    int d = d0 + lane * 4;
    float4 xv0 = *(const float4*)(xr0 + d);
    float4 xv1 = *(const float4*)(xr1 + d);
    unsigned short o0[4] = {f2bf(xv0.x), f2bf(xv0.y), f2bf(xv0.z), f2bf(xv0.w)};
    unsigned short o1[4] = {f2bf(xv1.x), f2bf(xv1.y), f2bf(xv1.z), f2bf(xv1.w)};
    *(uint2*)(xw0 + d) = *(const uint2*)o0;
    *(uint2*)(xw1 + d) = *(const uint2*)o1;
    double x00 = (double)xv0.x, x01 = (double)xv0.y, x02 = (double)xv0.z, x03 = (double)xv0.w;
    double x10 = (double)xv1.x, x11 = (double)xv1.y, x12 = (double)xv1.z, x13 = (double)xv1.w;
    const float* gs = &gws[cur][lane * 4];
#pragma unroll
    for (int e = 0; e < NEXP; e++) {
      float4 g = *(const float4*)(gs + e * 256);
      double g0 = (double)g.x, g1 = (double)g.y, g2 = (double)g.z, g3 = (double)g.w;
      double s0 = acc0[e], s1 = acc1[e];
      s0 = fma(x00, g0, s0); s0 = fma(x01, g1, s0);
      s0 = fma(x02, g2, s0); s0 = fma(x03, g3, s0);
      s1 = fma(x10, g0, s1); s1 = fma(x11, g1, s1);
      s1 = fma(x12, g2, s1); s1 = fma(x13, g3, s1);
      acc0[e] = s0; acc1[e] = s1;
    }
    __syncthreads();                              // chunk consumed; next chunk's loads drained
    cur ^= 1;
  }

  // butterfly reduce across 64 lanes (all lanes end with the totals)
#define RED(v) { v += __shfl_xor(v,32,64); v += __shfl_xor(v,16,64); v += __shfl_xor(v,8,64); \
                 v += __shfl_xor(v,4,64);  v += __shfl_xor(v,2,64);  v += __shfl_xor(v,1,64); }
#pragma unroll
  for (int e = 0; e < NEXP; e++) { RED(acc0[e]) RED(acc1[e]) }
#undef RED

#define TOPSEL(ACC, N) { \
    double v0 = -1e300, v1 = -1e300; int i0 = 0, i1 = 0; \
    _Pragma("unroll") \
    for (int e = 0; e < NEXP; e++) { \
      double v = ACC[e]; \
      if (v > v0) { v1 = v0; i1 = i0; v0 = v; i0 = e; } \
      else if (v > v1) { v1 = v; i1 = e; } \
    } \
    double ex = exp(v1 - v0); \
    double denom = 1.0 + ex; \
    eidx[N]  = make_int2(i0, i1); \
    pvals[N] = make_float2((float)(1.0 / denom), (float)(ex / denom)); \
  }
  if (lane == 0) TOPSEL(acc0, n0)
  if (lane == 1) TOPSEL(acc1, n0 + 1)
#undef TOPSEL
}

// ---------------- histogram: counts + colsum via LDS bins ----------------
__global__ __launch_bounds__(256) void hist_kernel(
    const int2* __restrict__ eidx, const float2* __restrict__ pvals,
    int* __restrict__ counts, float* __restrict__ colsum)
{
  __shared__ int   cbin[NEXP];
  __shared__ float lbin[NEXP];
  if (threadIdx.x < NEXP) { cbin[threadIdx.x] = 0; lbin[threadIdx.x] = 0.f; }
  __syncthreads();
  int n = blockIdx.x * 256 + threadIdx.x;
  int2 e = eidx[n];
  float2 p = pvals[n];
  atomicAdd(&cbin[e.x], 1);  atomicAdd(&lbin[e.x], p.x);
  atomicAdd(&cbin[e.y], 1);  atomicAdd(&lbin[e.y], p.y);
  __syncthreads();
  if (threadIdx.x < NEXP) {
    atomicAdd(&counts[threadIdx.x], cbin[threadIdx.x]);
    atomicAdd(&colsum[threadIdx.x], lbin[threadIdx.x]);
  }
}

// ---------------- scan bases (128-aligned segments) + loss ----------------
__global__ void scan_loss_kernel(const int* __restrict__ counts, int* __restrict__ base,
                                 const float* __restrict__ colsum, float* __restrict__ loss_out)
{
  if (threadIdx.x == 0 && blockIdx.x == 0) {
    int acc = 0;
    for (int e = 0; e < NEXP; e++) { base[e] = acc; acc += (counts[e] + 127) & ~127; }
    base[NEXP] = acc;
    double s = 0.0;
    for (int e = 0; e < NEXP; e++) { double c = (double)colsum[e]; s += c * c; }
    loss_out[0] = (float)(1.6 * s / ((double)NTOK * (double)NTOK));
  }
}

// ---------------- scatter: wave-aggregated cursor atomics; records slot positions ----------------
__global__ __launch_bounds__(256) void scatter_kernel(
    const int2* __restrict__ eidx, const int* __restrict__ base, int* __restrict__ cursor,
    int* __restrict__ tok, int2* __restrict__ spos)
{
  int n = blockIdx.x * 256 + threadIdx.x;
  int lane = threadIdx.x & 63;
  int2 e = eidx[n];
  int myE[2] = {e.x, e.y};
  int myPos[2];
#pragma unroll
  for (int s = 0; s < 2; s++) {
    int eq = myE[s];
#pragma unroll
    for (int q = 0; q < NEXP; q++) {
      unsigned long long m = __ballot(eq == q);
      if (eq == q) {
        int cnt = __popcll(m);
        int pre = __popcll(m & ((1ull << lane) - 1ull));
        int b = 0;
        if (pre == 0) b = atomicAdd(&cursor[q], cnt);
        int leader = __ffsll((long long)m) - 1;
        b = __shfl(b, leader, 64);
        int pos = base[q] + b + pre;
        tok[pos] = n;
        myPos[s] = pos;
      }
    }
  }
  spos[n] = make_int2(myPos[0], myPos[1]);
}

// ---------------- grouped expert down-proj: bf16 MFMA, 128x128, BK=64, 4 waves ----------------
// R7 post-mortem: residency & tile shape exhausted; residual = LDS read latency exposed at
// each kk-cluster start (ds_read -> immediately-dependent MFMA). R8 fix: FRAGMENT ROTATION.
// kk0 frags of tile t+1 are issued one full tile early (right after the buffer-ready
// barrier); kk1 frags are issued before the kk0 MFMA cluster; lgkmcnt(0) lands after 16
// MFMAs covered the latency. Barrier/vmcnt discipline unchanged (counted, never 0 mid-loop).
// FMA order per output element unchanged (kk0 then kk1, tiles in order) -> seg bit-identical.
__global__ __launch_bounds__(256, 2) void down_mfma_kernel(
    const unsigned short* __restrict__ xb, const unsigned short* __restrict__ dwb,
    const int* __restrict__ base, const int* __restrict__ tok,
    unsigned short* __restrict__ seg, int kcount)
{
  __shared__ unsigned short smem[32768];   // 2 x (A 8192 + B 8192) shorts = 64KB; epi 128x136

  int wg  = blockIdx.x;
  int cpx = gridDim.x >> 3;                 // blocks per XCD chunk (1152/8=144 or 576/8=72)
  int logical = (wg & 7) * cpx + (wg >> 3); // bijective XCD chunking
  int kh      = logical / DGRID_HALF;
  int r       = logical % DGRID_HALF;
  int slot0   = (r >> 2) * 128;             // slot-group
  int out0    = (r & 3) * 128;              // out-block fastest (A-tile reuse)

  if (slot0 >= base[NEXP]) return;          // uniform per block
  int e = 0;
#pragma unroll
  for (int q = 1; q < NEXP; q++) if (base[q] <= slot0) e = q;
  int kbase = kh * kcount * 64;

  int tid = threadIdx.x;
  const int l = tid & 63, w = tid >> 6;     // 4 waves
  const int wm = w & 1, wn = w >> 1;        // 2M x 2N
  const int lm = l & 15, quad = l >> 4;

  const unsigned short* agp[4];
  const unsigned short* bgp[4];
#pragma unroll
  for (int i = 0; i < 4; i++) {             // A,B: 128 rows = 16 groups, 4/wave each
    int g = w * 4 + i;
    int rr = g * 8 + (l & 7);
    int kc = l >> 3;
    int t = tok[slot0 + rr];
    agp[i] = xb + (size_t)(t < 0 ? 0 : t) * HID + kbase + kc * 8;
    bgp[i] = dwb + ((size_t)e * DWN + out0 + rr) * HID + kbase + kc * 8;
  }

  int am_off[4], bn_off[4];
#pragma unroll
  for (int mi = 0; mi < 4; mi++) {
    int m = wm * 64 + mi * 16 + lm;
    am_off[mi] = (m >> 3) * 512 + (m & 7) * 8 + quad * 64;
    int nn = wn * 64 + mi * 16 + lm;
    bn_off[mi] = (nn >> 3) * 512 + (nn & 7) * 8 + quad * 64;
  }

  f32x4 acc[4][4] = {};
  bf16x8 a0[4], b0[4], a1[4], b1[4];

  // stage tile T into buffer BUF (8 loads/wave)
#define DSTAGE(BUF, T) do {                                                   \
    int k0_ = (T) * 64;                                                       \
    unsigned short* Ap_ = smem + (BUF) * 16384;                               \
    _Pragma("unroll") for (int i = 0; i < 4; i++) {                           \
      int g_ = w * 4 + i;                                                     \
      ASYNC16(agp[i] + k0_, &Ap_[g_ * 512]);                                  \
      ASYNC16(bgp[i] + k0_, &Ap_[8192 + g_ * 512]);                           \
    }                                                                         \
  } while (0)

#define DMFMA(AA, BB) do {                                                    \
    __builtin_amdgcn_s_setprio(1);                                            \
    _Pragma("unroll") for (int mi = 0; mi < 4; mi++)                          \
      _Pragma("unroll") for (int ni = 0; ni < 4; ni++)                        \
        acc[mi][ni] = __builtin_amdgcn_mfma_f32_16x16x32_bf16(AA[mi], BB[ni], acc[mi][ni], 0, 0, 0); \
    __builtin_amdgcn_s_setprio(0);                                            \
  } while (0)

  // prologue: tiles 0,1 in flight; wait tile 0 (8 newest outstanding); preload tile0 kk0 frags
  DSTAGE(0, 0);
  DSTAGE(1, 1);
  asm volatile("s_waitcnt vmcnt(8)" ::: "memory");
  __builtin_amdgcn_s_barrier();
#pragma unroll
  for (int mi = 0; mi < 4; mi++) {
    a0[mi] = *(const bf16x8*)&smem[am_off[mi]];
    b0[mi] = *(const bf16x8*)&smem[8192 + bn_off[mi]];
  }

  for (int it = 0; it < kcount; ++it) {
    int cur = it & 1;
    unsigned short* As = smem + cur * 16384;
    unsigned short* Bs = As + 8192;
    // issue kk1 reads (consumed at end of this iteration)
#pragma unroll
    for (int mi = 0; mi < 4; mi++) {
      a1[mi] = *(const bf16x8*)&As[am_off[mi] + 256];
      b1[mi] = *(const bf16x8*)&Bs[bn_off[mi] + 256];
    }
    // MFMA kk0: inputs were issued one full tile ago -> no lgkm wait
    DMFMA(a0, b0);
    asm volatile("s_waitcnt lgkmcnt(0)" ::: "memory");   // all reads of buf[cur] done
    __builtin_amdgcn_sched_barrier(0);
    __builtin_amdgcn_s_barrier();                        // buf[cur] free for restage
    if (it + 2 < kcount) DSTAGE(cur, it + 2);
    if (it + 1 < kcount) {
      if (it + 2 < kcount) asm volatile("s_waitcnt vmcnt(8)" ::: "memory");
      else                 asm volatile("s_waitcnt vmcnt(0)" ::: "memory");
      __builtin_amdgcn_s_barrier();                      // buf[cur^1] ready
      unsigned short* An = smem + (cur ^ 1) * 16384;
      unsigned short* Bn = An + 8192;
      // early-issue next tile's kk0 frags (hide latency under MFMA kk1 + next barrier)
#pragma unroll
      for (int mi = 0; mi < 4; mi++) {
        a0[mi] = *(const bf16x8*)&An[am_off[mi]];
        b0[mi] = *(const bf16x8*)&Bn[bn_off[mi]];
      }
    }
    // MFMA kk1: inputs completed at the lgkmcnt(0) above
    DMFMA(a1, b1);
  }
#undef DMFMA
#undef DSTAGE

  // epilogue: stage bf16 tile in LDS (stride 136 shorts = 272B, 16B-aligned, bank-spread),
  // then fully-coalesced 16B global stores. No atomics.
  __syncthreads();
#pragma unroll
  for (int mi = 0; mi < 4; mi++)
#pragma unroll
    for (int reg = 0; reg < 4; reg++) {
      int m = wm * 64 + mi * 16 + quad * 4 + reg;
#pragma unroll
      for (int ni = 0; ni < 4; ni++) {
        int c = wn * 64 + ni * 16 + lm;
        smem[m * 136 + c] = f2bf(acc[mi][ni][reg]);
      }
    }
  __syncthreads();
#pragma unroll
  for (int it2 = 0; it2 < 8; it2++) {
    int chunk = it2 * 256 + tid;
    int row = chunk >> 4, off = (chunk & 15) * 8;
    uint4 v = *(const uint4*)&smem[row * 136 + off];
    *(uint4*)&seg[(size_t)kh * SEGHALF_SHORTS + (size_t)(slot0 + row) * 512 + out0 + off] = v;
  }
}

// ---------------- combine (gather 2 slots x ksplit halves) + bias + gelu_new -> h bf16 ----------------
__global__ __launch_bounds__(256) void combine_gelu_kernel(
    const unsigned short* __restrict__ seg, const int2* __restrict__ spos,
    const float2* __restrict__ pv, const int2* __restrict__ eix,
    const float* __restrict__ db, unsigned short* __restrict__ h, int ksplit)
{
  int n = blockIdx.x * 4 + (threadIdx.x >> 6);
  int lane = threadIdx.x & 63;
  int c0 = lane * 8;
  int2 sp = spos[n];
  float2 p = pv[n];
  int2 e = eix[n];

  float d0[8] = {0,0,0,0,0,0,0,0}, d1[8] = {0,0,0,0,0,0,0,0};
  for (int hh = 0; hh < ksplit; hh++) {
    uint4 u0 = *(const uint4*)(seg + (size_t)hh * SEGHALF_SHORTS + (size_t)sp.x * 512 + c0);
    uint4 u1 = *(const uint4*)(seg + (size_t)hh * SEGHALF_SHORTS + (size_t)sp.y * 512 + c0);
    const unsigned short* s0 = (const unsigned short*)&u0;
    const unsigned short* s1 = (const unsigned short*)&u1;
#pragma unroll
    for (int j = 0; j < 8; j++) { d0[j] += bf2f(s0[j]); d1[j] += bf2f(s1[j]); }
  }
  float b0[8], b1[8];
  *(float4*)&b0[0] = *(const float4*)(db + e.x * DWN + c0);
  *(float4*)&b0[4] = *(const float4*)(db + e.x * DWN + c0 + 4);
  *(float4*)&b1[0] = *(const float4*)(db + e.y * DWN + c0);
  *(float4*)&b1[4] = *(const float4*)(db + e.y * DWN + c0 + 4);

  unsigned short o[8];
#pragma unroll
  for (int j = 0; j < 8; j++) {
    float xx = p.x * (d0[j] + b0[j]) + p.y * (d1[j] + b1[j]);
    float inner = 0.7978845608028654f * (xx + 0.044715f * xx * xx * xx);
    o[j] = f2bf(0.5f * xx * (1.0f + tanhf(inner)));
  }
  *(uint4*)(h + (size_t)n * DWN + c0) = *(const uint4*)o;
}

// ---------------- up-proj: bf16 MFMA, 256x256, BK=64, K=512, 8 waves, counted-vmcnt ----------
// (passed R6/R7; unchanged) 8 loads/wave/tile, steady 16 outstanding, vmcnt(8) waits for the
// older tile only. Grid = 256 blocks = exactly 1/CU (no tail). XCD swizzle col-fastest.
__global__ __launch_bounds__(512, 2) void up_mfma_kernel(
    const unsigned short* __restrict__ h, const unsigned short* __restrict__ uwb,
    const float* __restrict__ ub, float* __restrict__ out)
{
  __shared__ unsigned short smem[65536];   // 2 x (A 16384 + B 16384) shorts = 128KB

  int wg  = blockIdx.x;                    // grid = 256
  int cpx = gridDim.x >> 3;                // 32
  int logical = (wg & 7) * cpx + (wg >> 3);
  int row0 = (logical >> 3) * 256;
  int col0 = (logical & 7) * 256;          // col fastest

  int tid = threadIdx.x;
  const int l = tid & 63, w = tid >> 6;    // 8 waves
  const int wm = w & 1, wn = w >> 1;       // 2M x 4N
  const int lm = l & 15, quad = l >> 4;

  const unsigned short* agp[4];
  const unsigned short* bgp[4];
#pragma unroll
  for (int i = 0; i < 4; i++) {            // A,B: 256 rows = 32 groups, 4/wave each
    int g = w * 4 + i;
    int rr = g * 8 + (l & 7);
    int kc = l >> 3;
    agp[i] = h   + (size_t)(row0 + rr) * DWN + kc * 8;
    bgp[i] = uwb + (size_t)(col0 + rr) * DWN + kc * 8;
  }

  int am_off[8], bn_off[4];
#pragma unroll
  for (int mi = 0; mi < 8; mi++) {
    int m = wm * 128 + mi * 16 + lm;
    am_off[mi] = (m >> 3) * 512 + (m & 7) * 8 + quad * 64;
  }
#pragma unroll
  for (int ni = 0; ni < 4; ni++) {
    int nn = wn * 64 + ni * 16 + lm;
    bn_off[ni] = (nn >> 3) * 512 + (nn & 7) * 8 + quad * 64;
  }

  f32x4 acc[8][4] = {};

#define USTAGE(BUF, T) do {                                                   \
    int k0_ = (T) * 64;                                                       \
    unsigned short* Ap_ = smem + (BUF) * 32768;                               \
    _Pragma("unroll") for (int i = 0; i < 4; i++) {                           \
      int g_ = w * 4 + i;                                                     \
      ASYNC16(agp[i] + k0_, &Ap_[g_ * 512]);                                  \
      ASYNC16(bgp[i] + k0_, &Ap_[16384 + g_ * 512]);                          \
    }                                                                         \
  } while (0)

  USTAGE(0, 0);
  USTAGE(1, 1);
  asm volatile("s_waitcnt vmcnt(8)" ::: "memory");
  __builtin_amdgcn_s_barrier();

  int cur = 0;
#define UTILE(STAGE_STMT, WAIT_STMT) do {                                     \
    unsigned short* As = smem + cur * 32768;                                  \
    unsigned short* Bs = As + 16384;                                          \
    bf16x8 a0[8], b0[4], a1[8], b1[4];                                        \
    _Pragma("unroll") for (int mi = 0; mi < 8; mi++) a0[mi] = *(const bf16x8*)&As[am_off[mi]]; \
    _Pragma("unroll") for (int ni = 0; ni < 4; ni++) b0[ni] = *(const bf16x8*)&Bs[bn_off[ni]]; \
    __builtin_amdgcn_s_setprio(1);                                            \
    _Pragma("unroll") for (int mi = 0; mi < 8; mi++)                          \
      _Pragma("unroll") for (int ni = 0; ni < 4; ni++)                        \
        acc[mi][ni] = __builtin_amdgcn_mfma_f32_16x16x32_bf16(a0[mi], b0[ni], acc[mi][ni], 0, 0, 0); \
    __builtin_amdgcn_s_setprio(0);                                            \
    _Pragma("unroll") for (int mi = 0; mi < 8; mi++) a1[mi] = *(const bf16x8*)&As[am_off[mi] + 256]; \
    _Pragma("unroll") for (int ni = 0; ni < 4; ni++) b1[ni] = *(const bf16x8*)&Bs[bn_off[ni] + 256]; \
    asm volatile("s_waitcnt lgkmcnt(0)" ::: "memory");                        \
    __builtin_amdgcn_sched_barrier(0);                                        \
    __builtin_amdgcn_s_barrier();                                             \
    STAGE_STMT;                                                               \
    __builtin_amdgcn_s_setprio(1);                                            \
    _Pragma("unroll") for (int mi = 0; mi < 8; mi++)                          \
      _Pragma("unroll") for (int ni = 0; ni < 4; ni++)                        \
        acc[mi][ni] = __builtin_amdgcn_mfma_f32_16x16x32_bf16(a1[mi], b1[ni], acc[mi][ni], 0, 0, 0); \
    __builtin_amdgcn_s_setprio(0);                                            \
    WAIT_STMT;                                                                \
  } while (0)

  const int nt = DWN / 64;   // 8
  for (int it = 0; it < nt - 2; ++it) {
    UTILE(USTAGE(cur, it + 2), VMWAIT_BAR(8));
    cur ^= 1;
  }
  UTILE(NOSTMT, VMWAIT_BAR(0));
  cur ^= 1;
  UTILE(NOSTMT, NOSTMT);
#undef UTILE
#undef USTAGE

  float ubv[4];
#pragma unroll
  for (int ni = 0; ni < 4; ni++)
    ubv[ni] = ub[col0 + wn * 64 + ni * 16 + lm];
#pragma unroll
  for (int mi = 0; mi < 8; mi++) {
#pragma unroll
    for (int reg = 0; reg < 4; reg++) {
      int m = row0 + wm * 128 + mi * 16 + quad * 4 + reg;
      float* orow = out + (size_t)m * HID;
#pragma unroll
      for (int ni = 0; ni < 4; ni++) {
        int gc = col0 + wn * 64 + ni * 16 + lm;
        orow[gc] = acc[mi][ni][reg] + ubv[ni];
      }
    }
  }
}

extern "C" void kernel_launch(void* const* d_in, const int* in_sizes, int n_in,
                              void* d_out, int out_size, void* d_ws, size_t ws_size,
                              hipStream_t stream)
{
  const float* x  = (const float*)d_in[0];
  const float* gw = (const float*)d_in[1];
  const float* dw = (const float*)d_in[2];
  const float* db = (const float*)d_in[3];
  const float* uw = (const float*)d_in[4];
  const float* ub = (const float*)d_in[5];
  float* out = (float*)d_out;

  char* ws = (char*)d_ws;
  unsigned short* xb   = (unsigned short*)(ws + OFF_XB);
  unsigned short* dwb  = (unsigned short*)(ws + OFF_DWB);
  unsigned short* uwb  = (unsigned short*)(ws + OFF_UWB);
  unsigned short* h    = (unsigned short*)(ws + OFF_H);
  unsigned short* seg  = (unsigned short*)(ws + OFF_SEG);
  int*    tok    = (int*)(ws + OFF_TOK);
  int2*   spos   = (int2*)(ws + OFF_SPOS);
  int2*   eidx   = (int2*)(ws + OFF_EIDX);
  float2* pvals  = (float2*)(ws + OFF_PVAL);
  int*    counts = (int*)(ws + OFF_COUNTS);
  int*    base   = (int*)(ws + OFF_BASE);
  int*    cursor = (int*)(ws + OFF_CURSOR);
  float*  colsum = (float*)(ws + OFF_COLSUM);

  // split-K only if the workspace is big enough (ws_size constant per session -> same work each call)
  const int ksplit = (ws_size >= (size_t)WS_NEED2) ? 2 : 1;
  const int kcount = (HID / 64) / ksplit;

  hipMemsetAsync(tok, 0xFF, PADSLOT * sizeof(int), stream);     // token = -1 padding
  hipMemsetAsync(counts, 0, 320, stream);                        // counts/base/cursor/colsum

  // x cast is fused into gate_kernel (reads x once, writes xb)
  cast8_kernel<<<(NEXP * DWN * HID) / 8 / 256, 256, 0, stream>>>(dw, dwb);
  cast8_kernel<<<(HID * DWN) / 8 / 256, 256, 0, stream>>>(uw, uwb);

  gate_kernel<<<NTOK / 8, 256, 0, stream>>>(x, gw, eidx, pvals, xb);
  hist_kernel<<<NTOK / 256, 256, 0, stream>>>(eidx, pvals, counts, colsum);
  scan_loss_kernel<<<1, 64, 0, stream>>>(counts, base, colsum, out + (size_t)NTOK * HID);
  scatter_kernel<<<NTOK / 256, 256, 0, stream>>>(eidx, base, cursor, tok, spos);

  down_mfma_kernel<<<DGRID_HALF * ksplit, 256, 0, stream>>>(xb, dwb, base, tok, seg, kcount);

  combine_gelu_kernel<<<NTOK / 4, 256, 0, stream>>>(seg, spos, pvals, eidx, db, h, ksplit);

  up_mfma_kernel<<<(NTOK / 256) * (HID / 256), 512, 0, stream>>>(h, uwb, ub, out);
}